// Round 4
// baseline (781.156 us; speedup 1.0000x reference)
//
#include <hip/hip_runtime.h>
#include <math.h>

#define N_NODES 100000
#define N_EDGES 1600000
#define HDIM    256
#define NGRAPH  64

#define SCAN_BLK 1024
#define SCAN_NB  ((N_NODES + SCAN_BLK - 1) / SCAN_BLK)  // 98

typedef __attribute__((ext_vector_type(8))) short bf16x8;
typedef __attribute__((ext_vector_type(4))) float f32x4;
typedef __attribute__((ext_vector_type(8))) unsigned short u16x8;

__device__ __forceinline__ ushort f2b(float f) {
    union { float f; unsigned u; } x; x.f = f;
    unsigned u = x.u;
    unsigned r = u + 0x7fffu + ((u >> 16) & 1u);
    return (ushort)(r >> 16);
}
__device__ __forceinline__ float b2f(ushort h) {
    union { unsigned u; float f; } x; x.u = ((unsigned)h) << 16;
    return x.f;
}

// ---------------- CSR build ----------------
__global__ void k_zero_int(int* __restrict__ p, int n) {
    int i = blockIdx.x * blockDim.x + threadIdx.x;
    if (i < n) p[i] = 0;
}

__global__ void k_count(const int* __restrict__ ei, int* __restrict__ cnt) {
    int e = blockIdx.x * blockDim.x + threadIdx.x;
    if (e < N_EDGES) atomicAdd(&cnt[ei[N_EDGES + e]], 1);
}

// phase 1: per-block exclusive scan -> rowptr (local), totals -> bsum
__global__ __launch_bounds__(1024) void k_scan1(const int* __restrict__ cnt,
                                                int* __restrict__ rowptr,
                                                int* __restrict__ bsum) {
    __shared__ int lds[SCAN_BLK];
    int t = threadIdx.x;
    int i = blockIdx.x * SCAN_BLK + t;
    int v = (i < N_NODES) ? cnt[i] : 0;
    lds[t] = v;
    __syncthreads();
    for (int off = 1; off < SCAN_BLK; off <<= 1) {
        int u = (t >= off) ? lds[t - off] : 0;
        __syncthreads();
        lds[t] += u;
        __syncthreads();
    }
    if (i < N_NODES) rowptr[i] = lds[t] - v;  // local exclusive
    if (t == SCAN_BLK - 1) bsum[blockIdx.x] = lds[t];
}

// phase 2: exclusive scan of the 98 block totals
__global__ __launch_bounds__(128) void k_scan2(int* __restrict__ bsum) {
    __shared__ int lds[128];
    int t = threadIdx.x;
    int v = (t < SCAN_NB) ? bsum[t] : 0;
    lds[t] = v;
    __syncthreads();
    for (int off = 1; off < 128; off <<= 1) {
        int u = (t >= off) ? lds[t - off] : 0;
        __syncthreads();
        lds[t] += u;
        __syncthreads();
    }
    if (t < SCAN_NB) bsum[t] = lds[t] - v;
}

// phase 3 merged with dinv: rowptr += block offset; dinv/xd/fill init
__global__ void k_dinv_fix(const int* __restrict__ cnt, const float* __restrict__ x,
                           const int* __restrict__ bsum,
                           float* __restrict__ dinv, float* __restrict__ xd,
                           int* __restrict__ fill, int* __restrict__ rowptr) {
    int i = blockIdx.x * blockDim.x + threadIdx.x;
    if (i < N_NODES) {
        rowptr[i] += bsum[i >> 10];
        float d = (float)(cnt[i] + 1);
        float dv = 1.0f / sqrtf(d);
        dinv[i] = dv;
        xd[i] = x[i] * dv;
        fill[i] = 0;
        if (i == 0) rowptr[N_NODES] = N_EDGES;
    }
}

__global__ void k_fill(const int* __restrict__ ei, const int* __restrict__ rowptr,
                       int* __restrict__ fill, int* __restrict__ colv) {
    int e = blockIdx.x * blockDim.x + threadIdx.x;
    if (e < N_EDGES) {
        int d = ei[N_EDGES + e];
        int pos = rowptr[d] + atomicAdd(&fill[d], 1);
        colv[pos] = ei[e];
    }
}

// layer-1 scalar aggregation
__global__ void k_s(const int* __restrict__ rowptr, const int* __restrict__ colv,
                    const float* __restrict__ xd, const float* __restrict__ dinv,
                    float* __restrict__ sv) {
    int i = blockIdx.x * blockDim.x + threadIdx.x;
    if (i >= N_NODES) return;
    float acc = xd[i];
    int s = rowptr[i], e = rowptr[i + 1];
    for (int k = s; k < e; ++k) acc += xd[colv[k]];
    sv[i] = dinv[i] * acc;
}

// h1[i][j] = relu(s[i]*W1[j] + b1[j])  -> bf16
__global__ __launch_bounds__(256) void k_h1(const float* __restrict__ sv,
                                            const float* __restrict__ W1,
                                            const float* __restrict__ b1,
                                            ushort* __restrict__ h) {
    int wid = threadIdx.x >> 6, lane = threadIdx.x & 63;
    int node = blockIdx.x * 4 + wid;
    if (node >= N_NODES) return;
    int c4 = lane * 4;
    float s = sv[node];
    float4 w = *(const float4*)&W1[c4];
    float4 b = *(const float4*)&b1[c4];
    ushort4 o;
    o.x = f2b(fmaxf(s * w.x + b.x, 0.f));
    o.y = f2b(fmaxf(s * w.y + b.y, 0.f));
    o.z = f2b(fmaxf(s * w.z + b.z, 0.f));
    o.w = f2b(fmaxf(s * w.w + b.w, 0.f));
    *(ushort4*)&h[(size_t)node * HDIM + c4] = o;
}

// pack W (f32 [256][256]) into bf16 MFMA fragment order (works as A or B frag)
__global__ __launch_bounds__(256) void k_packW(const float* __restrict__ W,
                                               ushort* __restrict__ Wp) {
    int t = blockIdx.x * 256 + threadIdx.x;  // [0, 8192)
    if (t >= 8 * 16 * 64) return;
    int lane = t & 63;
    int nt = (t >> 6) & 15;
    int k0 = t >> 10;
    int col = nt * 16 + (lane & 15);
    int kb = k0 * 32 + (lane >> 4) * 8;
    ushort o[8];
#pragma unroll
    for (int j = 0; j < 8; ++j) o[j] = f2b(W[(size_t)(kb + j) * HDIM + col]);
    *(ushort4*)&Wp[(size_t)t * 8 + 0] = make_ushort4(o[0], o[1], o[2], o[3]);
    *(ushort4*)&Wp[(size_t)t * 8 + 4] = make_ushort4(o[4], o[5], o[6], o[7]);
}

// MFMA GEMM (operand-swapped): D[feat][node] = mfma(A=W^T frag, B=h-row frag).
// Lane holds 4 consecutive feats of one node per nt -> ushort4 stores.
__global__ __launch_bounds__(256) void k_gemm_mfma(const ushort* __restrict__ A,
                                                   const ushort* __restrict__ Wp,
                                                   const float* __restrict__ dinv,
                                                   ushort* __restrict__ C) {
    int tid = threadIdx.x;
    int wave = tid >> 6, lane = tid & 63;
    int r0 = blockIdx.x * 64 + wave * 16;
    int node = r0 + (lane & 15);
    int kgrp = lane >> 4;
    bool rowok = node < N_NODES;

    f32x4 acc[16];
#pragma unroll
    for (int nt = 0; nt < 16; ++nt) acc[nt] = (f32x4){0.f, 0.f, 0.f, 0.f};

    const ushort* ap = A + (size_t)(rowok ? node : 0) * HDIM + kgrp * 8;
#pragma unroll 1
    for (int k0 = 0; k0 < 8; ++k0) {
        bf16x8 b = *(const bf16x8*)(ap + k0 * 32);
        if (!rowok) b = (bf16x8){0, 0, 0, 0, 0, 0, 0, 0};
        const ushort* wp = Wp + ((size_t)k0 * 1024 + lane) * 8;
#pragma unroll
        for (int nt = 0; nt < 16; ++nt) {
            bf16x8 a = *(const bf16x8*)(wp + (size_t)nt * 512);
            acc[nt] = __builtin_amdgcn_mfma_f32_16x16x32_bf16(a, b, acc[nt], 0, 0, 0);
        }
    }

    if (rowok) {
        float dv = dinv[node];
        size_t base = (size_t)node * HDIM + kgrp * 4;
#pragma unroll
        for (int nt = 0; nt < 16; ++nt) {
            ushort4 o;
            o.x = f2b(acc[nt][0] * dv);
            o.y = f2b(acc[nt][1] * dv);
            o.z = f2b(acc[nt][2] * dv);
            o.w = f2b(acc[nt][3] * dv);
            *(ushort4*)&C[base + nt * 16] = o;
        }
    }
}

// aggregation: h[i] = relu(dinv[i]*(g[i] + sum_src g[src]) + b)
// wave per node; half-wave covers one 512B row; 4 neighbors per wave-iter.
__global__ __launch_bounds__(256) void k_agg(const ushort* __restrict__ g,
                                             const int* __restrict__ rowptr,
                                             const int* __restrict__ colv,
                                             const float* __restrict__ dinv,
                                             const float* __restrict__ bias,
                                             ushort* __restrict__ hout) {
    int wid = threadIdx.x >> 6, lane = threadIdx.x & 63;
    int node = blockIdx.x * 4 + wid;
    if (node >= N_NODES) return;
    int half = lane >> 5;
    int l32 = lane & 31;
    int c8 = l32 * 8;
    float acc[8];
    if (half == 0) {
        u16x8 v = *(const u16x8*)&g[(size_t)node * HDIM + c8];
#pragma unroll
        for (int j = 0; j < 8; ++j) acc[j] = b2f(v[j]);
    } else {
#pragma unroll
        for (int j = 0; j < 8; ++j) acc[j] = 0.f;
    }
    int s = rowptr[node], e = rowptr[node + 1];
    int i = s;
#pragma unroll 2
    for (; i + 4 <= e; i += 4) {
        int na = colv[i + half * 2];
        int nb = colv[i + half * 2 + 1];
        u16x8 va = *(const u16x8*)&g[(size_t)na * HDIM + c8];
        u16x8 vb = *(const u16x8*)&g[(size_t)nb * HDIM + c8];
#pragma unroll
        for (int j = 0; j < 8; ++j) acc[j] += b2f(va[j]);
#pragma unroll
        for (int j = 0; j < 8; ++j) acc[j] += b2f(vb[j]);
    }
    for (; i + 2 <= e; i += 2) {
        int n = colv[i + half];
        u16x8 v = *(const u16x8*)&g[(size_t)n * HDIM + c8];
#pragma unroll
        for (int j = 0; j < 8; ++j) acc[j] += b2f(v[j]);
    }
    if (i < e && half == 0) {
        int n = colv[i];
        u16x8 v = *(const u16x8*)&g[(size_t)n * HDIM + c8];
#pragma unroll
        for (int j = 0; j < 8; ++j) acc[j] += b2f(v[j]);
    }
#pragma unroll
    for (int j = 0; j < 8; ++j) acc[j] += __shfl_xor(acc[j], 32);
    if (half == 0) {
        float dv = dinv[node];
        float4 bl = *(const float4*)&bias[c8];
        float4 bh = *(const float4*)&bias[c8 + 4];
        float bj[8] = {bl.x, bl.y, bl.z, bl.w, bh.x, bh.y, bh.z, bh.w};
        u16x8 ov;
#pragma unroll
        for (int j = 0; j < 8; ++j)
            ov[j] = f2b(fmaxf(fmaf(acc[j], dv, bj[j]), 0.f));
        *(u16x8*)&hout[(size_t)node * HDIM + c8] = ov;
    }
}

__global__ __launch_bounds__(128) void k_bounds(const int* __restrict__ batch,
                                                int* __restrict__ startb,
                                                float* __restrict__ pooled) {
    int t = threadIdx.x;
    if (t <= NGRAPH) {
        int lo = 0, hi = N_NODES;
        while (lo < hi) {
            int mid = (lo + hi) >> 1;
            if (batch[mid] < t) lo = mid + 1; else hi = mid;
        }
        startb[t] = lo;
    }
    for (int i = t; i < NGRAPH * HDIM; i += 128) pooled[i] = 0.f;
}

__global__ __launch_bounds__(256) void k_pool(const ushort* __restrict__ h,
                                              const int* __restrict__ startb,
                                              float* __restrict__ pooled) {
    int b = blockIdx.x >> 3, c = blockIdx.x & 7;
    int s0 = startb[b], e0 = startb[b + 1];
    int len = e0 - s0;
    if (len <= 0) return;
    int per = (len + 7) >> 3;
    int is = s0 + c * per;
    int ie = min(is + per, e0);
    if (is >= ie) return;
    int j = threadIdx.x;
    float sum = 0.f;
    for (int n = is; n < ie; ++n) sum += b2f(h[(size_t)n * HDIM + j]);
    atomicAdd(&pooled[b * HDIM + j], sum);
}

// final MLP (feat built in-kernel from pooled/cnt + svm)
__global__ __launch_bounds__(128) void k_mlp(const float* __restrict__ pooled,
                                             const int* __restrict__ startb,
                                             const float* __restrict__ svm,
                                             const float* __restrict__ Wf1,
                                             const float* __restrict__ bf1,
                                             const float* __restrict__ Wf2,
                                             const float* __restrict__ bf2,
                                             float* __restrict__ out) {
    __shared__ float fl[257];
    __shared__ float hl[128];
    int b = blockIdx.x;
    int j = threadIdx.x;
    float cntb = fmaxf((float)(startb[b + 1] - startb[b]), 1.0f);
    for (int k = j; k < 256; k += 128) fl[k] = pooled[b * HDIM + k] / cntb;
    if (j == 0) fl[256] = svm[b];
    __syncthreads();
    float acc = bf1[j];
    for (int k = 0; k < 257; ++k) acc = fmaf(fl[k], Wf1[k * 128 + j], acc);
    hl[j] = fmaxf(acc, 0.f);
    __syncthreads();
    if (j < 6) {
        float o = bf2[j];
        for (int k = 0; k < 128; ++k) o = fmaf(hl[k], Wf2[k * 6 + j], o);
        out[b * 6 + j] = o;
    }
}

static inline size_t al256(size_t x) { return (x + 255) & ~(size_t)255; }

extern "C" void kernel_launch(void* const* d_in, const int* in_sizes, int n_in,
                              void* d_out, int out_size, void* d_ws, size_t ws_size,
                              hipStream_t stream) {
    const float* x    = (const float*)d_in[0];
    const int*   ei   = (const int*)d_in[1];
    const int*   batch= (const int*)d_in[2];
    const float* svm  = (const float*)d_in[3];
    const float* W1   = (const float*)d_in[4];
    const float* b1   = (const float*)d_in[5];
    const float* W2   = (const float*)d_in[6];
    const float* b2   = (const float*)d_in[7];
    const float* W3   = (const float*)d_in[8];
    const float* b3   = (const float*)d_in[9];
    const float* Wf1  = (const float*)d_in[10];
    const float* bf1  = (const float*)d_in[11];
    const float* Wf2  = (const float*)d_in[12];
    const float* bf2  = (const float*)d_in[13];
    float* out = (float*)d_out;

    char* w = (char*)d_ws;
    int*    cnt    = (int*)w;    w += al256((size_t)N_NODES * 4);
    int*    rowptr = (int*)w;    w += al256((size_t)(N_NODES + 1) * 4);
    int*    fill   = (int*)w;    w += al256((size_t)N_NODES * 4);
    int*    colv   = (int*)w;    w += al256((size_t)N_EDGES * 4);
    float*  dinv   = (float*)w;  w += al256((size_t)N_NODES * 4);
    float*  xd     = (float*)w;  w += al256((size_t)N_NODES * 4);
    float*  sv     = (float*)w;  w += al256((size_t)N_NODES * 4);
    int*    startb = (int*)w;    w += al256(65 * 4);
    int*    bsum   = (int*)w;    w += al256((size_t)SCAN_NB * 4);
    float*  pooled = (float*)w;  w += al256((size_t)NGRAPH * HDIM * 4);
    ushort* Wp2    = (ushort*)w; w += al256((size_t)8 * 16 * 64 * 8 * 2);
    ushort* Wp3    = (ushort*)w; w += al256((size_t)8 * 16 * 64 * 8 * 2);
    ushort* bigA   = (ushort*)w; w += al256((size_t)N_NODES * HDIM * 2);
    ushort* bigB   = (ushort*)w; w += al256((size_t)N_NODES * HDIM * 2);

    const int nblkN = (N_NODES + 255) / 256;
    const int nblkE = (N_EDGES + 255) / 256;
    const int nblkW = (N_NODES + 3) / 4;
    const int nblkG = (N_NODES + 63) / 64;

    // CSR build
    k_zero_int<<<nblkN, 256, 0, stream>>>(cnt, N_NODES);
    k_count<<<nblkE, 256, 0, stream>>>(ei, cnt);
    k_scan1<<<SCAN_NB, SCAN_BLK, 0, stream>>>(cnt, rowptr, bsum);
    k_scan2<<<1, 128, 0, stream>>>(bsum);
    k_dinv_fix<<<nblkN, 256, 0, stream>>>(cnt, x, bsum, dinv, xd, fill, rowptr);
    k_fill<<<nblkE, 256, 0, stream>>>(ei, rowptr, fill, colv);

    // W packing (layer 2/3)
    k_packW<<<32, 256, 0, stream>>>(W2, Wp2);
    k_packW<<<32, 256, 0, stream>>>(W3, Wp3);

    // layer 1 (rank-1)
    k_s<<<nblkN, 256, 0, stream>>>(rowptr, colv, xd, dinv, sv);
    k_h1<<<nblkW, 256, 0, stream>>>(sv, W1, b1, bigA);

    // layer 2
    k_gemm_mfma<<<nblkG, 256, 0, stream>>>(bigA, Wp2, dinv, bigB);
    k_agg<<<nblkW, 256, 0, stream>>>(bigB, rowptr, colv, dinv, b2, bigA);
    // layer 3
    k_gemm_mfma<<<nblkG, 256, 0, stream>>>(bigA, Wp3, dinv, bigB);
    k_agg<<<nblkW, 256, 0, stream>>>(bigB, rowptr, colv, dinv, b3, bigA);

    // pooling + head
    k_bounds<<<1, 128, 0, stream>>>(batch, startb, pooled);
    k_pool<<<NGRAPH * 8, 256, 0, stream>>>(bigA, startb, pooled);
    k_mlp<<<NGRAPH, 128, 0, stream>>>(pooled, startb, svm, Wf1, bf1, Wf2, bf2, out);
}

// Round 5
// 565.908 us; speedup vs baseline: 1.3804x; 1.3804x over previous
//
#include <hip/hip_runtime.h>
#include <math.h>

#define N_NODES 100000
#define N_EDGES 1600000
#define HDIM    256
#define NGRAPH  64

#define SCAN_BLK 1024
#define SCAN_NB  ((N_NODES + SCAN_BLK - 1) / SCAN_BLK)  // 98

typedef __attribute__((ext_vector_type(8))) short bf16x8;
typedef __attribute__((ext_vector_type(4))) float f32x4;
typedef __attribute__((ext_vector_type(8))) unsigned short u16x8;

__device__ __forceinline__ ushort f2b(float f) {
    union { float f; unsigned u; } x; x.f = f;
    unsigned u = x.u;
    unsigned r = u + 0x7fffu + ((u >> 16) & 1u);
    return (ushort)(r >> 16);
}
__device__ __forceinline__ float b2f(ushort h) {
    union { unsigned u; float f; } x; x.u = ((unsigned)h) << 16;
    return x.f;
}

// ---------------- CSR build ----------------
// count in-degree AND record each edge's slot within its row
__global__ void k_count(const int* __restrict__ ei, int* __restrict__ cnt,
                        int* __restrict__ slot) {
    int e = blockIdx.x * blockDim.x + threadIdx.x;
    if (e < N_EDGES) slot[e] = atomicAdd(&cnt[ei[N_EDGES + e]], 1);
}

// phase 1: per-block exclusive scan -> rowptr (local), totals -> bsum
__global__ __launch_bounds__(1024) void k_scan1(const int* __restrict__ cnt,
                                                int* __restrict__ rowptr,
                                                int* __restrict__ bsum) {
    __shared__ int lds[SCAN_BLK];
    int t = threadIdx.x;
    int i = blockIdx.x * SCAN_BLK + t;
    int v = (i < N_NODES) ? cnt[i] : 0;
    lds[t] = v;
    __syncthreads();
    for (int off = 1; off < SCAN_BLK; off <<= 1) {
        int u = (t >= off) ? lds[t - off] : 0;
        __syncthreads();
        lds[t] += u;
        __syncthreads();
    }
    if (i < N_NODES) rowptr[i] = lds[t] - v;  // local exclusive
    if (t == SCAN_BLK - 1) bsum[blockIdx.x] = lds[t];
}

// phase 2: exclusive scan of the 98 block totals
__global__ __launch_bounds__(128) void k_scan2(int* __restrict__ bsum) {
    __shared__ int lds[128];
    int t = threadIdx.x;
    int v = (t < SCAN_NB) ? bsum[t] : 0;
    lds[t] = v;
    __syncthreads();
    for (int off = 1; off < 128; off <<= 1) {
        int u = (t >= off) ? lds[t - off] : 0;
        __syncthreads();
        lds[t] += u;
        __syncthreads();
    }
    if (t < SCAN_NB) bsum[t] = lds[t] - v;
}

// phase 3 merged with dinv: rowptr += block offset; dinv/xd init
__global__ void k_dinv_fix(const int* __restrict__ cnt, const float* __restrict__ x,
                           const int* __restrict__ bsum,
                           float* __restrict__ dinv, float* __restrict__ xd,
                           int* __restrict__ rowptr) {
    int i = blockIdx.x * blockDim.x + threadIdx.x;
    if (i < N_NODES) {
        rowptr[i] += bsum[i >> 10];
        float d = (float)(cnt[i] + 1);
        float dv = 1.0f / sqrtf(d);
        dinv[i] = dv;
        xd[i] = x[i] * dv;
        if (i == 0) rowptr[N_NODES] = N_EDGES;
    }
}

// atomic-free CSR fill using precomputed slots
__global__ void k_fill(const int* __restrict__ ei, const int* __restrict__ rowptr,
                       const int* __restrict__ slot, int* __restrict__ colv) {
    int e = blockIdx.x * blockDim.x + threadIdx.x;
    if (e < N_EDGES) {
        int d = ei[N_EDGES + e];
        colv[rowptr[d] + slot[e]] = ei[e];
    }
}

// layer-1 scalar aggregation
__global__ void k_s(const int* __restrict__ rowptr, const int* __restrict__ colv,
                    const float* __restrict__ xd, const float* __restrict__ dinv,
                    float* __restrict__ sv) {
    int i = blockIdx.x * blockDim.x + threadIdx.x;
    if (i >= N_NODES) return;
    float acc = xd[i];
    int s = rowptr[i], e = rowptr[i + 1];
    for (int k = s; k < e; ++k) acc += xd[colv[k]];
    sv[i] = dinv[i] * acc;
}

// h1[i][j] = relu(s[i]*W1[j] + b1[j])  -> bf16
__global__ __launch_bounds__(256) void k_h1(const float* __restrict__ sv,
                                            const float* __restrict__ W1,
                                            const float* __restrict__ b1,
                                            ushort* __restrict__ h) {
    int wid = threadIdx.x >> 6, lane = threadIdx.x & 63;
    int node = blockIdx.x * 4 + wid;
    if (node >= N_NODES) return;
    int c4 = lane * 4;
    float s = sv[node];
    float4 w = *(const float4*)&W1[c4];
    float4 b = *(const float4*)&b1[c4];
    ushort4 o;
    o.x = f2b(fmaxf(s * w.x + b.x, 0.f));
    o.y = f2b(fmaxf(s * w.y + b.y, 0.f));
    o.z = f2b(fmaxf(s * w.z + b.z, 0.f));
    o.w = f2b(fmaxf(s * w.w + b.w, 0.f));
    *(ushort4*)&h[(size_t)node * HDIM + c4] = o;
}

// pack W (f32 [256][256]) into bf16 MFMA fragment order
__global__ __launch_bounds__(256) void k_packW(const float* __restrict__ W,
                                               ushort* __restrict__ Wp) {
    int t = blockIdx.x * 256 + threadIdx.x;  // [0, 8192)
    if (t >= 8 * 16 * 64) return;
    int lane = t & 63;
    int nt = (t >> 6) & 15;
    int k0 = t >> 10;
    int col = nt * 16 + (lane & 15);
    int kb = k0 * 32 + (lane >> 4) * 8;
    ushort o[8];
#pragma unroll
    for (int j = 0; j < 8; ++j) o[j] = f2b(W[(size_t)(kb + j) * HDIM + col]);
    *(ushort4*)&Wp[(size_t)t * 8 + 0] = make_ushort4(o[0], o[1], o[2], o[3]);
    *(ushort4*)&Wp[(size_t)t * 8 + 4] = make_ushort4(o[4], o[5], o[6], o[7]);
}

// MFMA GEMM (operand-swapped, 32 nodes/wave): D[feat][node] = mfma(Wfrag, hfrag).
// Each Wp fragment feeds 2 MFMAs; block of 4 waves covers 128 nodes.
__global__ __launch_bounds__(256) void k_gemm_mfma(const ushort* __restrict__ A,
                                                   const ushort* __restrict__ Wp,
                                                   const float* __restrict__ dinv,
                                                   ushort* __restrict__ C) {
    int tid = threadIdx.x;
    int wave = tid >> 6, lane = tid & 63;
    int r0 = blockIdx.x * 128 + wave * 32;
    int kgrp = lane >> 4;
    int node0 = r0 + (lane & 15);
    int node1 = node0 + 16;
    bool ok0 = node0 < N_NODES, ok1 = node1 < N_NODES;

    f32x4 acc0[16], acc1[16];
#pragma unroll
    for (int nt = 0; nt < 16; ++nt) {
        acc0[nt] = (f32x4){0.f, 0.f, 0.f, 0.f};
        acc1[nt] = (f32x4){0.f, 0.f, 0.f, 0.f};
    }

    const ushort* ap0 = A + (size_t)(ok0 ? node0 : 0) * HDIM + kgrp * 8;
    const ushort* ap1 = A + (size_t)(ok1 ? node1 : 0) * HDIM + kgrp * 8;
#pragma unroll 1
    for (int k0 = 0; k0 < 8; ++k0) {
        bf16x8 b0 = *(const bf16x8*)(ap0 + k0 * 32);
        bf16x8 b1 = *(const bf16x8*)(ap1 + k0 * 32);
        if (!ok0) b0 = (bf16x8){0, 0, 0, 0, 0, 0, 0, 0};
        if (!ok1) b1 = (bf16x8){0, 0, 0, 0, 0, 0, 0, 0};
        const ushort* wp = Wp + ((size_t)k0 * 1024 + lane) * 8;
#pragma unroll
        for (int nt = 0; nt < 16; ++nt) {
            bf16x8 a = *(const bf16x8*)(wp + (size_t)nt * 512);
            acc0[nt] = __builtin_amdgcn_mfma_f32_16x16x32_bf16(a, b0, acc0[nt], 0, 0, 0);
            acc1[nt] = __builtin_amdgcn_mfma_f32_16x16x32_bf16(a, b1, acc1[nt], 0, 0, 0);
        }
    }

    if (ok0) {
        float dv = dinv[node0];
        size_t base = (size_t)node0 * HDIM + kgrp * 4;
#pragma unroll
        for (int nt = 0; nt < 16; ++nt) {
            ushort4 o;
            o.x = f2b(acc0[nt][0] * dv);
            o.y = f2b(acc0[nt][1] * dv);
            o.z = f2b(acc0[nt][2] * dv);
            o.w = f2b(acc0[nt][3] * dv);
            *(ushort4*)&C[base + nt * 16] = o;
        }
    }
    if (ok1) {
        float dv = dinv[node1];
        size_t base = (size_t)node1 * HDIM + kgrp * 4;
#pragma unroll
        for (int nt = 0; nt < 16; ++nt) {
            ushort4 o;
            o.x = f2b(acc1[nt][0] * dv);
            o.y = f2b(acc1[nt][1] * dv);
            o.z = f2b(acc1[nt][2] * dv);
            o.w = f2b(acc1[nt][3] * dv);
            *(ushort4*)&C[base + nt * 16] = o;
        }
    }
}

// aggregation: h[i] = relu(dinv[i]*(g[i] + sum_src g[src]) + b)
__global__ __launch_bounds__(256) void k_agg(const ushort* __restrict__ g,
                                             const int* __restrict__ rowptr,
                                             const int* __restrict__ colv,
                                             const float* __restrict__ dinv,
                                             const float* __restrict__ bias,
                                             ushort* __restrict__ hout) {
    int wid = threadIdx.x >> 6, lane = threadIdx.x & 63;
    int node = blockIdx.x * 4 + wid;
    if (node >= N_NODES) return;
    int half = lane >> 5;
    int l32 = lane & 31;
    int c8 = l32 * 8;
    float acc[8];
    if (half == 0) {
        u16x8 v = *(const u16x8*)&g[(size_t)node * HDIM + c8];
#pragma unroll
        for (int j = 0; j < 8; ++j) acc[j] = b2f(v[j]);
    } else {
#pragma unroll
        for (int j = 0; j < 8; ++j) acc[j] = 0.f;
    }
    int s = rowptr[node], e = rowptr[node + 1];
    int i = s;
#pragma unroll 2
    for (; i + 4 <= e; i += 4) {
        int na = colv[i + half * 2];
        int nb = colv[i + half * 2 + 1];
        u16x8 va = *(const u16x8*)&g[(size_t)na * HDIM + c8];
        u16x8 vb = *(const u16x8*)&g[(size_t)nb * HDIM + c8];
#pragma unroll
        for (int j = 0; j < 8; ++j) acc[j] += b2f(va[j]);
#pragma unroll
        for (int j = 0; j < 8; ++j) acc[j] += b2f(vb[j]);
    }
    for (; i + 2 <= e; i += 2) {
        int n = colv[i + half];
        u16x8 v = *(const u16x8*)&g[(size_t)n * HDIM + c8];
#pragma unroll
        for (int j = 0; j < 8; ++j) acc[j] += b2f(v[j]);
    }
    if (i < e && half == 0) {
        int n = colv[i];
        u16x8 v = *(const u16x8*)&g[(size_t)n * HDIM + c8];
#pragma unroll
        for (int j = 0; j < 8; ++j) acc[j] += b2f(v[j]);
    }
#pragma unroll
    for (int j = 0; j < 8; ++j) acc[j] += __shfl_xor(acc[j], 32);
    if (half == 0) {
        float dv = dinv[node];
        float4 bl = *(const float4*)&bias[c8];
        float4 bh = *(const float4*)&bias[c8 + 4];
        float bj[8] = {bl.x, bl.y, bl.z, bl.w, bh.x, bh.y, bh.z, bh.w};
        u16x8 ov;
#pragma unroll
        for (int j = 0; j < 8; ++j)
            ov[j] = f2b(fmaxf(fmaf(acc[j], dv, bj[j]), 0.f));
        *(u16x8*)&hout[(size_t)node * HDIM + c8] = ov;
    }
}

__global__ __launch_bounds__(128) void k_bounds(const int* __restrict__ batch,
                                                int* __restrict__ startb,
                                                float* __restrict__ pooled) {
    int t = threadIdx.x;
    if (t <= NGRAPH) {
        int lo = 0, hi = N_NODES;
        while (lo < hi) {
            int mid = (lo + hi) >> 1;
            if (batch[mid] < t) lo = mid + 1; else hi = mid;
        }
        startb[t] = lo;
    }
    for (int i = t; i < NGRAPH * HDIM; i += 128) pooled[i] = 0.f;
}

__global__ __launch_bounds__(256) void k_pool(const ushort* __restrict__ h,
                                              const int* __restrict__ startb,
                                              float* __restrict__ pooled) {
    int b = blockIdx.x >> 3, c = blockIdx.x & 7;
    int s0 = startb[b], e0 = startb[b + 1];
    int len = e0 - s0;
    if (len <= 0) return;
    int per = (len + 7) >> 3;
    int is = s0 + c * per;
    int ie = min(is + per, e0);
    if (is >= ie) return;
    int j = threadIdx.x;
    float sum = 0.f;
    for (int n = is; n < ie; ++n) sum += b2f(h[(size_t)n * HDIM + j]);
    atomicAdd(&pooled[b * HDIM + j], sum);
}

// final MLP (feat built in-kernel from pooled/cnt + svm)
__global__ __launch_bounds__(128) void k_mlp(const float* __restrict__ pooled,
                                             const int* __restrict__ startb,
                                             const float* __restrict__ svm,
                                             const float* __restrict__ Wf1,
                                             const float* __restrict__ bf1,
                                             const float* __restrict__ Wf2,
                                             const float* __restrict__ bf2,
                                             float* __restrict__ out) {
    __shared__ float fl[257];
    __shared__ float hl[128];
    int b = blockIdx.x;
    int j = threadIdx.x;
    float cntb = fmaxf((float)(startb[b + 1] - startb[b]), 1.0f);
    for (int k = j; k < 256; k += 128) fl[k] = pooled[b * HDIM + k] / cntb;
    if (j == 0) fl[256] = svm[b];
    __syncthreads();
    float acc = bf1[j];
    for (int k = 0; k < 257; ++k) acc = fmaf(fl[k], Wf1[k * 128 + j], acc);
    hl[j] = fmaxf(acc, 0.f);
    __syncthreads();
    if (j < 6) {
        float o = bf2[j];
        for (int k = 0; k < 128; ++k) o = fmaf(hl[k], Wf2[k * 6 + j], o);
        out[b * 6 + j] = o;
    }
}

static inline size_t al256(size_t x) { return (x + 255) & ~(size_t)255; }

extern "C" void kernel_launch(void* const* d_in, const int* in_sizes, int n_in,
                              void* d_out, int out_size, void* d_ws, size_t ws_size,
                              hipStream_t stream) {
    const float* x    = (const float*)d_in[0];
    const int*   ei   = (const int*)d_in[1];
    const int*   batch= (const int*)d_in[2];
    const float* svm  = (const float*)d_in[3];
    const float* W1   = (const float*)d_in[4];
    const float* b1   = (const float*)d_in[5];
    const float* W2   = (const float*)d_in[6];
    const float* b2   = (const float*)d_in[7];
    const float* W3   = (const float*)d_in[8];
    const float* b3   = (const float*)d_in[9];
    const float* Wf1  = (const float*)d_in[10];
    const float* bf1  = (const float*)d_in[11];
    const float* Wf2  = (const float*)d_in[12];
    const float* bf2  = (const float*)d_in[13];
    float* out = (float*)d_out;

    char* w = (char*)d_ws;
    int*    cnt    = (int*)w;    w += al256((size_t)N_NODES * 4);
    int*    rowptr = (int*)w;    w += al256((size_t)(N_NODES + 1) * 4);
    int*    slot   = (int*)w;    w += al256((size_t)N_EDGES * 4);
    int*    colv   = (int*)w;    w += al256((size_t)N_EDGES * 4);
    float*  dinv   = (float*)w;  w += al256((size_t)N_NODES * 4);
    float*  xd     = (float*)w;  w += al256((size_t)N_NODES * 4);
    float*  sv     = (float*)w;  w += al256((size_t)N_NODES * 4);
    int*    startb = (int*)w;    w += al256(65 * 4);
    int*    bsum   = (int*)w;    w += al256((size_t)SCAN_NB * 4);
    float*  pooled = (float*)w;  w += al256((size_t)NGRAPH * HDIM * 4);
    ushort* Wp2    = (ushort*)w; w += al256((size_t)8 * 16 * 64 * 8 * 2);
    ushort* Wp3    = (ushort*)w; w += al256((size_t)8 * 16 * 64 * 8 * 2);
    ushort* bigA   = (ushort*)w; w += al256((size_t)N_NODES * HDIM * 2);
    ushort* bigB   = (ushort*)w; w += al256((size_t)N_NODES * HDIM * 2);

    const int nblkN = (N_NODES + 255) / 256;
    const int nblkE = (N_EDGES + 255) / 256;
    const int nblkW = (N_NODES + 3) / 4;
    const int nblkG = (N_NODES + 127) / 128;  // gemm: 128 nodes/block

    // CSR build
    hipMemsetAsync(cnt, 0, (size_t)N_NODES * 4, stream);
    k_count<<<nblkE, 256, 0, stream>>>(ei, cnt, slot);
    k_scan1<<<SCAN_NB, SCAN_BLK, 0, stream>>>(cnt, rowptr, bsum);
    k_scan2<<<1, 128, 0, stream>>>(bsum);
    k_dinv_fix<<<nblkN, 256, 0, stream>>>(cnt, x, bsum, dinv, xd, rowptr);
    k_fill<<<nblkE, 256, 0, stream>>>(ei, rowptr, slot, colv);

    // W packing (layer 2/3)
    k_packW<<<32, 256, 0, stream>>>(W2, Wp2);
    k_packW<<<32, 256, 0, stream>>>(W3, Wp3);

    // layer 1 (rank-1)
    k_s<<<nblkN, 256, 0, stream>>>(rowptr, colv, xd, dinv, sv);
    k_h1<<<nblkW, 256, 0, stream>>>(sv, W1, b1, bigA);

    // layer 2
    k_gemm_mfma<<<nblkG, 256, 0, stream>>>(bigA, Wp2, dinv, bigB);
    k_agg<<<nblkW, 256, 0, stream>>>(bigB, rowptr, colv, dinv, b2, bigA);
    // layer 3
    k_gemm_mfma<<<nblkG, 256, 0, stream>>>(bigA, Wp3, dinv, bigB);
    k_agg<<<nblkW, 256, 0, stream>>>(bigB, rowptr, colv, dinv, b3, bigA);

    // pooling + head
    k_bounds<<<1, 128, 0, stream>>>(batch, startb, pooled);
    k_pool<<<NGRAPH * 8, 256, 0, stream>>>(bigA, startb, pooled);
    k_mlp<<<NGRAPH, 128, 0, stream>>>(pooled, startb, svm, Wf1, bf1, Wf2, bf2, out);
}

// Round 6
// 543.920 us; speedup vs baseline: 1.4362x; 1.0404x over previous
//
#include <hip/hip_runtime.h>
#include <math.h>

#define N_NODES 100000
#define N_EDGES 1600000
#define HDIM    256
#define NGRAPH  64

#define SCAN_BLK 1024
#define SCAN_NB  ((N_NODES + SCAN_BLK - 1) / SCAN_BLK)  // 98

typedef __attribute__((ext_vector_type(8))) short bf16x8;
typedef __attribute__((ext_vector_type(4))) float f32x4;
typedef __attribute__((ext_vector_type(8))) unsigned short u16x8;

__device__ __forceinline__ ushort f2b(float f) {
    union { float f; unsigned u; } x; x.f = f;
    unsigned u = x.u;
    unsigned r = u + 0x7fffu + ((u >> 16) & 1u);
    return (ushort)(r >> 16);
}
__device__ __forceinline__ float b2f(ushort h) {
    union { unsigned u; float f; } x; x.u = ((unsigned)h) << 16;
    return x.f;
}

// ---------------- CSR build ----------------
__global__ void k_count(const int* __restrict__ ei, int* __restrict__ cnt,
                        int* __restrict__ slot) {
    int e = blockIdx.x * blockDim.x + threadIdx.x;
    if (e < N_EDGES) slot[e] = atomicAdd(&cnt[ei[N_EDGES + e]], 1);
}

__global__ __launch_bounds__(1024) void k_scan1(const int* __restrict__ cnt,
                                                int* __restrict__ rowptr,
                                                int* __restrict__ bsum) {
    __shared__ int lds[SCAN_BLK];
    int t = threadIdx.x;
    int i = blockIdx.x * SCAN_BLK + t;
    int v = (i < N_NODES) ? cnt[i] : 0;
    lds[t] = v;
    __syncthreads();
    for (int off = 1; off < SCAN_BLK; off <<= 1) {
        int u = (t >= off) ? lds[t - off] : 0;
        __syncthreads();
        lds[t] += u;
        __syncthreads();
    }
    if (i < N_NODES) rowptr[i] = lds[t] - v;
    if (t == SCAN_BLK - 1) bsum[blockIdx.x] = lds[t];
}

__global__ __launch_bounds__(128) void k_scan2(int* __restrict__ bsum) {
    __shared__ int lds[128];
    int t = threadIdx.x;
    int v = (t < SCAN_NB) ? bsum[t] : 0;
    lds[t] = v;
    __syncthreads();
    for (int off = 1; off < 128; off <<= 1) {
        int u = (t >= off) ? lds[t - off] : 0;
        __syncthreads();
        lds[t] += u;
        __syncthreads();
    }
    if (t < SCAN_NB) bsum[t] = lds[t] - v;
}

__global__ void k_dinv_fix(const int* __restrict__ cnt, const float* __restrict__ x,
                           const int* __restrict__ bsum,
                           float* __restrict__ dinv, float* __restrict__ xd,
                           int* __restrict__ rowptr) {
    int i = blockIdx.x * blockDim.x + threadIdx.x;
    if (i < N_NODES) {
        rowptr[i] += bsum[i >> 10];
        float d = (float)(cnt[i] + 1);
        float dv = 1.0f / sqrtf(d);
        dinv[i] = dv;
        xd[i] = x[i] * dv;
        if (i == 0) rowptr[N_NODES] = N_EDGES;
    }
}

__global__ void k_fill(const int* __restrict__ ei, const int* __restrict__ rowptr,
                       const int* __restrict__ slot, int* __restrict__ colv) {
    int e = blockIdx.x * blockDim.x + threadIdx.x;
    if (e < N_EDGES) {
        int d = ei[N_EDGES + e];
        colv[rowptr[d] + slot[e]] = ei[e];
    }
}

// layer-1 scalar aggregation
__global__ void k_s(const int* __restrict__ rowptr, const int* __restrict__ colv,
                    const float* __restrict__ xd, const float* __restrict__ dinv,
                    float* __restrict__ sv) {
    int i = blockIdx.x * blockDim.x + threadIdx.x;
    if (i >= N_NODES) return;
    float acc = xd[i];
    int s = rowptr[i], e = rowptr[i + 1];
    for (int k = s; k < e; ++k) acc += xd[colv[k]];
    sv[i] = dinv[i] * acc;
}

// pack W (f32 [256][256]) into bf16 MFMA fragment order; 2 matrices in 1 launch
__global__ __launch_bounds__(256) void k_packW2(const float* __restrict__ Wa,
                                                ushort* __restrict__ Wpa,
                                                const float* __restrict__ Wb,
                                                ushort* __restrict__ Wpb) {
    int bid = blockIdx.x;
    const float* W = (bid < 32) ? Wa : Wb;
    ushort* Wp = (bid < 32) ? Wpa : Wpb;
    int t = (bid & 31) * 256 + threadIdx.x;  // [0, 8192)
    int lane = t & 63;
    int nt = (t >> 6) & 15;
    int k0 = t >> 10;
    int col = nt * 16 + (lane & 15);
    int kb = k0 * 32 + (lane >> 4) * 8;
    ushort o[8];
#pragma unroll
    for (int j = 0; j < 8; ++j) o[j] = f2b(W[(size_t)(kb + j) * HDIM + col]);
    *(ushort4*)&Wp[(size_t)t * 8 + 0] = make_ushort4(o[0], o[1], o[2], o[3]);
    *(ushort4*)&Wp[(size_t)t * 8 + 4] = make_ushort4(o[4], o[5], o[6], o[7]);
}

// Fused layer1 + GEMM2: B-fragments computed on the fly from sv (rank-1 h1).
// D[feat][node], 32 nodes/wave, epilogue scales by dinv -> bf16 rows of C.
__global__ __launch_bounds__(256) void k_gemm_h1(const float* __restrict__ sv,
                                                 const float* __restrict__ W1,
                                                 const float* __restrict__ b1,
                                                 const ushort* __restrict__ Wp,
                                                 const float* __restrict__ dinv,
                                                 ushort* __restrict__ C) {
    int tid = threadIdx.x;
    int wave = tid >> 6, lane = tid & 63;
    int r0 = blockIdx.x * 128 + wave * 32;
    int kgrp = lane >> 4;
    int node0 = r0 + (lane & 15);
    int node1 = node0 + 16;
    bool ok0 = node0 < N_NODES, ok1 = node1 < N_NODES;
    float s0 = ok0 ? sv[node0] : 0.f;
    float s1 = ok1 ? sv[node1] : 0.f;

    f32x4 acc0[16], acc1[16];
#pragma unroll
    for (int nt = 0; nt < 16; ++nt) {
        acc0[nt] = (f32x4){0.f, 0.f, 0.f, 0.f};
        acc1[nt] = (f32x4){0.f, 0.f, 0.f, 0.f};
    }

#pragma unroll 1
    for (int k0 = 0; k0 < 8; ++k0) {
        int kb = k0 * 32 + kgrp * 8;
        float4 wa = *(const float4*)&W1[kb];
        float4 wb = *(const float4*)&W1[kb + 4];
        float4 ba = *(const float4*)&b1[kb];
        float4 bb = *(const float4*)&b1[kb + 4];
        float w[8] = {wa.x, wa.y, wa.z, wa.w, wb.x, wb.y, wb.z, wb.w};
        float bi[8] = {ba.x, ba.y, ba.z, ba.w, bb.x, bb.y, bb.z, bb.w};
        bf16x8 b0, b1v;
#pragma unroll
        for (int j = 0; j < 8; ++j) {
            b0[j] = (short)f2b(fmaxf(fmaf(s0, w[j], bi[j]), 0.f));
            b1v[j] = (short)f2b(fmaxf(fmaf(s1, w[j], bi[j]), 0.f));
        }
        const ushort* wp = Wp + ((size_t)k0 * 1024 + lane) * 8;
#pragma unroll
        for (int nt = 0; nt < 16; ++nt) {
            bf16x8 a = *(const bf16x8*)(wp + (size_t)nt * 512);
            acc0[nt] = __builtin_amdgcn_mfma_f32_16x16x32_bf16(a, b0, acc0[nt], 0, 0, 0);
            acc1[nt] = __builtin_amdgcn_mfma_f32_16x16x32_bf16(a, b1v, acc1[nt], 0, 0, 0);
        }
    }

    if (ok0) {
        float dv = dinv[node0];
        size_t base = (size_t)node0 * HDIM + kgrp * 4;
#pragma unroll
        for (int nt = 0; nt < 16; ++nt) {
            ushort4 o;
            o.x = f2b(acc0[nt][0] * dv);
            o.y = f2b(acc0[nt][1] * dv);
            o.z = f2b(acc0[nt][2] * dv);
            o.w = f2b(acc0[nt][3] * dv);
            *(ushort4*)&C[base + nt * 16] = o;
        }
    }
    if (ok1) {
        float dv = dinv[node1];
        size_t base = (size_t)node1 * HDIM + kgrp * 4;
#pragma unroll
        for (int nt = 0; nt < 16; ++nt) {
            ushort4 o;
            o.x = f2b(acc1[nt][0] * dv);
            o.y = f2b(acc1[nt][1] * dv);
            o.z = f2b(acc1[nt][2] * dv);
            o.w = f2b(acc1[nt][3] * dv);
            *(ushort4*)&C[base + nt * 16] = o;
        }
    }
}

// standard MFMA GEMM (layer 3), bf16 A from global
__global__ __launch_bounds__(256) void k_gemm_mfma(const ushort* __restrict__ A,
                                                   const ushort* __restrict__ Wp,
                                                   const float* __restrict__ dinv,
                                                   ushort* __restrict__ C) {
    int tid = threadIdx.x;
    int wave = tid >> 6, lane = tid & 63;
    int r0 = blockIdx.x * 128 + wave * 32;
    int kgrp = lane >> 4;
    int node0 = r0 + (lane & 15);
    int node1 = node0 + 16;
    bool ok0 = node0 < N_NODES, ok1 = node1 < N_NODES;

    f32x4 acc0[16], acc1[16];
#pragma unroll
    for (int nt = 0; nt < 16; ++nt) {
        acc0[nt] = (f32x4){0.f, 0.f, 0.f, 0.f};
        acc1[nt] = (f32x4){0.f, 0.f, 0.f, 0.f};
    }

    const ushort* ap0 = A + (size_t)(ok0 ? node0 : 0) * HDIM + kgrp * 8;
    const ushort* ap1 = A + (size_t)(ok1 ? node1 : 0) * HDIM + kgrp * 8;
#pragma unroll 1
    for (int k0 = 0; k0 < 8; ++k0) {
        bf16x8 b0 = *(const bf16x8*)(ap0 + k0 * 32);
        bf16x8 b1 = *(const bf16x8*)(ap1 + k0 * 32);
        if (!ok0) b0 = (bf16x8){0, 0, 0, 0, 0, 0, 0, 0};
        if (!ok1) b1 = (bf16x8){0, 0, 0, 0, 0, 0, 0, 0};
        const ushort* wp = Wp + ((size_t)k0 * 1024 + lane) * 8;
#pragma unroll
        for (int nt = 0; nt < 16; ++nt) {
            bf16x8 a = *(const bf16x8*)(wp + (size_t)nt * 512);
            acc0[nt] = __builtin_amdgcn_mfma_f32_16x16x32_bf16(a, b0, acc0[nt], 0, 0, 0);
            acc1[nt] = __builtin_amdgcn_mfma_f32_16x16x32_bf16(a, b1, acc1[nt], 0, 0, 0);
        }
    }

    if (ok0) {
        float dv = dinv[node0];
        size_t base = (size_t)node0 * HDIM + kgrp * 4;
#pragma unroll
        for (int nt = 0; nt < 16; ++nt) {
            ushort4 o;
            o.x = f2b(acc0[nt][0] * dv);
            o.y = f2b(acc0[nt][1] * dv);
            o.z = f2b(acc0[nt][2] * dv);
            o.w = f2b(acc0[nt][3] * dv);
            *(ushort4*)&C[base + nt * 16] = o;
        }
    }
    if (ok1) {
        float dv = dinv[node1];
        size_t base = (size_t)node1 * HDIM + kgrp * 4;
#pragma unroll
        for (int nt = 0; nt < 16; ++nt) {
            ushort4 o;
            o.x = f2b(acc1[nt][0] * dv);
            o.y = f2b(acc1[nt][1] * dv);
            o.z = f2b(acc1[nt][2] * dv);
            o.w = f2b(acc1[nt][3] * dv);
            *(ushort4*)&C[base + nt * 16] = o;
        }
    }
}

// aggregation: h[i] = relu(dinv[i]*(g[i] + sum_src g[src]) + b)
// wave per node; half-wave covers one 512B row; 8 neighbors per wave-iter.
__global__ __launch_bounds__(256) void k_agg(const ushort* __restrict__ g,
                                             const int* __restrict__ rowptr,
                                             const int* __restrict__ colv,
                                             const float* __restrict__ dinv,
                                             const float* __restrict__ bias,
                                             ushort* __restrict__ hout) {
    int wid = threadIdx.x >> 6, lane = threadIdx.x & 63;
    int node = blockIdx.x * 4 + wid;
    if (node >= N_NODES) return;
    int half = lane >> 5;
    int l32 = lane & 31;
    int c8 = l32 * 8;
    float acc[8];
    if (half == 0) {
        u16x8 v = *(const u16x8*)&g[(size_t)node * HDIM + c8];
#pragma unroll
        for (int j = 0; j < 8; ++j) acc[j] = b2f(v[j]);
    } else {
#pragma unroll
        for (int j = 0; j < 8; ++j) acc[j] = 0.f;
    }
    int s = rowptr[node], e = rowptr[node + 1];
    int i = s;
    // 8 neighbors per wave iteration: 4 independent row-loads per half-wave
    for (; i + 8 <= e; i += 8) {
        int base = i + half * 4;
        int n0 = colv[base + 0];
        int n1 = colv[base + 1];
        int n2 = colv[base + 2];
        int n3 = colv[base + 3];
        u16x8 v0 = *(const u16x8*)&g[(size_t)n0 * HDIM + c8];
        u16x8 v1 = *(const u16x8*)&g[(size_t)n1 * HDIM + c8];
        u16x8 v2 = *(const u16x8*)&g[(size_t)n2 * HDIM + c8];
        u16x8 v3 = *(const u16x8*)&g[(size_t)n3 * HDIM + c8];
#pragma unroll
        for (int j = 0; j < 8; ++j)
            acc[j] += (b2f(v0[j]) + b2f(v1[j])) + (b2f(v2[j]) + b2f(v3[j]));
    }
    if (i + 4 <= e) {
        int base = i + half * 2;
        int n0 = colv[base + 0];
        int n1 = colv[base + 1];
        u16x8 v0 = *(const u16x8*)&g[(size_t)n0 * HDIM + c8];
        u16x8 v1 = *(const u16x8*)&g[(size_t)n1 * HDIM + c8];
#pragma unroll
        for (int j = 0; j < 8; ++j) acc[j] += b2f(v0[j]) + b2f(v1[j]);
        i += 4;
    }
    if (i + 2 <= e) {
        int n = colv[i + half];
        u16x8 v = *(const u16x8*)&g[(size_t)n * HDIM + c8];
#pragma unroll
        for (int j = 0; j < 8; ++j) acc[j] += b2f(v[j]);
        i += 2;
    }
    if (i < e && half == 0) {
        int n = colv[i];
        u16x8 v = *(const u16x8*)&g[(size_t)n * HDIM + c8];
#pragma unroll
        for (int j = 0; j < 8; ++j) acc[j] += b2f(v[j]);
    }
#pragma unroll
    for (int j = 0; j < 8; ++j) acc[j] += __shfl_xor(acc[j], 32);
    if (half == 0) {
        float dv = dinv[node];
        float4 bl = *(const float4*)&bias[c8];
        float4 bh = *(const float4*)&bias[c8 + 4];
        float bj[8] = {bl.x, bl.y, bl.z, bl.w, bh.x, bh.y, bh.z, bh.w};
        u16x8 ov;
#pragma unroll
        for (int j = 0; j < 8; ++j)
            ov[j] = f2b(fmaxf(fmaf(acc[j], dv, bj[j]), 0.f));
        *(u16x8*)&hout[(size_t)node * HDIM + c8] = ov;
    }
}

__global__ __launch_bounds__(128) void k_bounds(const int* __restrict__ batch,
                                                int* __restrict__ startb,
                                                float* __restrict__ pooled) {
    int t = threadIdx.x;
    if (t <= NGRAPH) {
        int lo = 0, hi = N_NODES;
        while (lo < hi) {
            int mid = (lo + hi) >> 1;
            if (batch[mid] < t) lo = mid + 1; else hi = mid;
        }
        startb[t] = lo;
    }
    for (int i = t; i < NGRAPH * HDIM; i += 128) pooled[i] = 0.f;
}

__global__ __launch_bounds__(256) void k_pool(const ushort* __restrict__ h,
                                              const int* __restrict__ startb,
                                              float* __restrict__ pooled) {
    int b = blockIdx.x >> 3, c = blockIdx.x & 7;
    int s0 = startb[b], e0 = startb[b + 1];
    int len = e0 - s0;
    if (len <= 0) return;
    int per = (len + 7) >> 3;
    int is = s0 + c * per;
    int ie = min(is + per, e0);
    if (is >= ie) return;
    int j = threadIdx.x;
    float sum = 0.f;
    for (int n = is; n < ie; ++n) sum += b2f(h[(size_t)n * HDIM + j]);
    atomicAdd(&pooled[b * HDIM + j], sum);
}

__global__ __launch_bounds__(128) void k_mlp(const float* __restrict__ pooled,
                                             const int* __restrict__ startb,
                                             const float* __restrict__ svm,
                                             const float* __restrict__ Wf1,
                                             const float* __restrict__ bf1,
                                             const float* __restrict__ Wf2,
                                             const float* __restrict__ bf2,
                                             float* __restrict__ out) {
    __shared__ float fl[257];
    __shared__ float hl[128];
    int b = blockIdx.x;
    int j = threadIdx.x;
    float cntb = fmaxf((float)(startb[b + 1] - startb[b]), 1.0f);
    for (int k = j; k < 256; k += 128) fl[k] = pooled[b * HDIM + k] / cntb;
    if (j == 0) fl[256] = svm[b];
    __syncthreads();
    float acc = bf1[j];
    for (int k = 0; k < 257; ++k) acc = fmaf(fl[k], Wf1[k * 128 + j], acc);
    hl[j] = fmaxf(acc, 0.f);
    __syncthreads();
    if (j < 6) {
        float o = bf2[j];
        for (int k = 0; k < 128; ++k) o = fmaf(hl[k], Wf2[k * 6 + j], o);
        out[b * 6 + j] = o;
    }
}

static inline size_t al256(size_t x) { return (x + 255) & ~(size_t)255; }

extern "C" void kernel_launch(void* const* d_in, const int* in_sizes, int n_in,
                              void* d_out, int out_size, void* d_ws, size_t ws_size,
                              hipStream_t stream) {
    const float* x    = (const float*)d_in[0];
    const int*   ei   = (const int*)d_in[1];
    const int*   batch= (const int*)d_in[2];
    const float* svm  = (const float*)d_in[3];
    const float* W1   = (const float*)d_in[4];
    const float* b1   = (const float*)d_in[5];
    const float* W2   = (const float*)d_in[6];
    const float* b2   = (const float*)d_in[7];
    const float* W3   = (const float*)d_in[8];
    const float* b3   = (const float*)d_in[9];
    const float* Wf1  = (const float*)d_in[10];
    const float* bf1  = (const float*)d_in[11];
    const float* Wf2  = (const float*)d_in[12];
    const float* bf2  = (const float*)d_in[13];
    float* out = (float*)d_out;

    char* w = (char*)d_ws;
    int*    cnt    = (int*)w;    w += al256((size_t)N_NODES * 4);
    int*    rowptr = (int*)w;    w += al256((size_t)(N_NODES + 1) * 4);
    int*    slot   = (int*)w;    w += al256((size_t)N_EDGES * 4);
    int*    colv   = (int*)w;    w += al256((size_t)N_EDGES * 4);
    float*  dinv   = (float*)w;  w += al256((size_t)N_NODES * 4);
    float*  xd     = (float*)w;  w += al256((size_t)N_NODES * 4);
    float*  sv     = (float*)w;  w += al256((size_t)N_NODES * 4);
    int*    startb = (int*)w;    w += al256(65 * 4);
    int*    bsum   = (int*)w;    w += al256((size_t)SCAN_NB * 4);
    float*  pooled = (float*)w;  w += al256((size_t)NGRAPH * HDIM * 4);
    ushort* Wp2    = (ushort*)w; w += al256((size_t)8 * 16 * 64 * 8 * 2);
    ushort* Wp3    = (ushort*)w; w += al256((size_t)8 * 16 * 64 * 8 * 2);
    ushort* bigA   = (ushort*)w; w += al256((size_t)N_NODES * HDIM * 2);
    ushort* bigB   = (ushort*)w; w += al256((size_t)N_NODES * HDIM * 2);

    const int nblkN = (N_NODES + 255) / 256;
    const int nblkE = (N_EDGES + 255) / 256;
    const int nblkW = (N_NODES + 3) / 4;
    const int nblkG = (N_NODES + 127) / 128;

    // CSR build
    hipMemsetAsync(cnt, 0, (size_t)N_NODES * 4, stream);
    k_count<<<nblkE, 256, 0, stream>>>(ei, cnt, slot);
    k_scan1<<<SCAN_NB, SCAN_BLK, 0, stream>>>(cnt, rowptr, bsum);
    k_scan2<<<1, 128, 0, stream>>>(bsum);
    k_dinv_fix<<<nblkN, 256, 0, stream>>>(cnt, x, bsum, dinv, xd, rowptr);
    k_fill<<<nblkE, 256, 0, stream>>>(ei, rowptr, slot, colv);

    // W packing (both layers, one launch)
    k_packW2<<<64, 256, 0, stream>>>(W2, Wp2, W3, Wp3);

    // layer 1 scalar agg
    k_s<<<nblkN, 256, 0, stream>>>(rowptr, colv, xd, dinv, sv);

    // layer 2 (h1 fused into gemm)
    k_gemm_h1<<<nblkG, 256, 0, stream>>>(sv, W1, b1, Wp2, dinv, bigB);
    k_agg<<<nblkW, 256, 0, stream>>>(bigB, rowptr, colv, dinv, b2, bigA);
    // layer 3
    k_gemm_mfma<<<nblkG, 256, 0, stream>>>(bigA, Wp3, dinv, bigB);
    k_agg<<<nblkW, 256, 0, stream>>>(bigB, rowptr, colv, dinv, b3, bigA);

    // pooling + head
    k_bounds<<<1, 128, 0, stream>>>(batch, startb, pooled);
    k_pool<<<NGRAPH * 8, 256, 0, stream>>>(bigA, startb, pooled);
    k_mlp<<<NGRAPH, 128, 0, stream>>>(pooled, startb, svm, Wf1, bf1, Wf2, bf2, out);
}

// Round 7
// 538.645 us; speedup vs baseline: 1.4502x; 1.0098x over previous
//
#include <hip/hip_runtime.h>
#include <math.h>

#define N_NODES 100000
#define N_EDGES 1600000
#define HDIM    256
#define NGRAPH  64

#define SCAN_BLK 1024
#define SCAN_NB  ((N_NODES + SCAN_BLK - 1) / SCAN_BLK)  // 98

typedef __attribute__((ext_vector_type(8))) short bf16x8;
typedef __attribute__((ext_vector_type(4))) float f32x4;
typedef __attribute__((ext_vector_type(8))) unsigned short u16x8;

__device__ __forceinline__ ushort f2b(float f) {
    union { float f; unsigned u; } x; x.f = f;
    unsigned u = x.u;
    unsigned r = u + 0x7fffu + ((u >> 16) & 1u);
    return (ushort)(r >> 16);
}
__device__ __forceinline__ float b2f(ushort h) {
    union { unsigned u; float f; } x; x.u = ((unsigned)h) << 16;
    return x.f;
}

// ---------------- CSR build ----------------
__global__ void k_count(const int* __restrict__ ei, int* __restrict__ cnt,
                        int* __restrict__ slot) {
    int e = blockIdx.x * blockDim.x + threadIdx.x;
    if (e < N_EDGES) slot[e] = atomicAdd(&cnt[ei[N_EDGES + e]], 1);
}

__global__ __launch_bounds__(1024) void k_scan1(const int* __restrict__ cnt,
                                                int* __restrict__ rowptr,
                                                int* __restrict__ bsum) {
    __shared__ int lds[SCAN_BLK];
    int t = threadIdx.x;
    int i = blockIdx.x * SCAN_BLK + t;
    int v = (i < N_NODES) ? cnt[i] : 0;
    lds[t] = v;
    __syncthreads();
    for (int off = 1; off < SCAN_BLK; off <<= 1) {
        int u = (t >= off) ? lds[t - off] : 0;
        __syncthreads();
        lds[t] += u;
        __syncthreads();
    }
    if (i < N_NODES) rowptr[i] = lds[t] - v;
    if (t == SCAN_BLK - 1) bsum[blockIdx.x] = lds[t];
}

__global__ __launch_bounds__(128) void k_scan2(int* __restrict__ bsum) {
    __shared__ int lds[128];
    int t = threadIdx.x;
    int v = (t < SCAN_NB) ? bsum[t] : 0;
    lds[t] = v;
    __syncthreads();
    for (int off = 1; off < 128; off <<= 1) {
        int u = (t >= off) ? lds[t - off] : 0;
        __syncthreads();
        lds[t] += u;
        __syncthreads();
    }
    if (t < SCAN_NB) bsum[t] = lds[t] - v;
}

__global__ void k_dinv_fix(const int* __restrict__ cnt, const float* __restrict__ x,
                           const int* __restrict__ bsum,
                           float* __restrict__ dinv, float* __restrict__ xd,
                           int* __restrict__ rowptr) {
    int i = blockIdx.x * blockDim.x + threadIdx.x;
    if (i < N_NODES) {
        rowptr[i] += bsum[i >> 10];
        float d = (float)(cnt[i] + 1);
        float dv = 1.0f / sqrtf(d);
        dinv[i] = dv;
        xd[i] = x[i] * dv;
        if (i == 0) rowptr[N_NODES] = N_EDGES;
    }
}

__global__ void k_fill(const int* __restrict__ ei, const int* __restrict__ rowptr,
                       const int* __restrict__ slot, int* __restrict__ colv) {
    int e = blockIdx.x * blockDim.x + threadIdx.x;
    if (e < N_EDGES) {
        int d = ei[N_EDGES + e];
        colv[rowptr[d] + slot[e]] = ei[e];
    }
}

// layer-1 scalar aggregation -> sd[i] = (s_i, dinv_i)
__global__ void k_s(const int* __restrict__ rowptr, const int* __restrict__ colv,
                    const float* __restrict__ xd, const float* __restrict__ dinv,
                    float2* __restrict__ sd) {
    int i = blockIdx.x * blockDim.x + threadIdx.x;
    if (i >= N_NODES) return;
    float acc = xd[i];
    int s = rowptr[i], e = rowptr[i + 1];
    for (int k = s; k < e; ++k) acc += xd[colv[k]];
    float dv = dinv[i];
    sd[i] = make_float2(dv * acc, dv);
}

// Layer-2 aggregation via rank-1 structure (exact fp32):
// M[i][k] = dinv_i * sum_{j in N(i)+i} dinv_j * relu(s_j*W1[k] + b1[k])
// wave per node, lane handles 4 consecutive features.
__global__ __launch_bounds__(256) void k_aggM(const int* __restrict__ rowptr,
                                              const int* __restrict__ colv,
                                              const float2* __restrict__ sd,
                                              const float* __restrict__ W1,
                                              const float* __restrict__ b1,
                                              ushort* __restrict__ M) {
    int wid = threadIdx.x >> 6, lane = threadIdx.x & 63;
    int node = blockIdx.x * 4 + wid;
    if (node >= N_NODES) return;
    int c4 = lane * 4;
    float4 w = *(const float4*)&W1[c4];
    float4 b = *(const float4*)&b1[c4];
    float2 self = sd[node];
    float a0, a1, a2, a3;
    {
        float s = self.x, dv = self.y;
        a0 = dv * fmaxf(fmaf(s, w.x, b.x), 0.f);
        a1 = dv * fmaxf(fmaf(s, w.y, b.y), 0.f);
        a2 = dv * fmaxf(fmaf(s, w.z, b.z), 0.f);
        a3 = dv * fmaxf(fmaf(s, w.w, b.w), 0.f);
    }
    int s0 = rowptr[node], e0 = rowptr[node + 1];
    int i = s0;
    for (; i + 4 <= e0; i += 4) {
        int n0 = colv[i], n1 = colv[i + 1], n2 = colv[i + 2], n3 = colv[i + 3];
        float2 p0 = sd[n0], p1 = sd[n1], p2 = sd[n2], p3 = sd[n3];
        a0 += p0.y * fmaxf(fmaf(p0.x, w.x, b.x), 0.f);
        a1 += p0.y * fmaxf(fmaf(p0.x, w.y, b.y), 0.f);
        a2 += p0.y * fmaxf(fmaf(p0.x, w.z, b.z), 0.f);
        a3 += p0.y * fmaxf(fmaf(p0.x, w.w, b.w), 0.f);
        a0 += p1.y * fmaxf(fmaf(p1.x, w.x, b.x), 0.f);
        a1 += p1.y * fmaxf(fmaf(p1.x, w.y, b.y), 0.f);
        a2 += p1.y * fmaxf(fmaf(p1.x, w.z, b.z), 0.f);
        a3 += p1.y * fmaxf(fmaf(p1.x, w.w, b.w), 0.f);
        a0 += p2.y * fmaxf(fmaf(p2.x, w.x, b.x), 0.f);
        a1 += p2.y * fmaxf(fmaf(p2.x, w.y, b.y), 0.f);
        a2 += p2.y * fmaxf(fmaf(p2.x, w.z, b.z), 0.f);
        a3 += p2.y * fmaxf(fmaf(p2.x, w.w, b.w), 0.f);
        a0 += p3.y * fmaxf(fmaf(p3.x, w.x, b.x), 0.f);
        a1 += p3.y * fmaxf(fmaf(p3.x, w.y, b.y), 0.f);
        a2 += p3.y * fmaxf(fmaf(p3.x, w.z, b.z), 0.f);
        a3 += p3.y * fmaxf(fmaf(p3.x, w.w, b.w), 0.f);
    }
    for (; i < e0; ++i) {
        float2 p = sd[colv[i]];
        a0 += p.y * fmaxf(fmaf(p.x, w.x, b.x), 0.f);
        a1 += p.y * fmaxf(fmaf(p.x, w.y, b.y), 0.f);
        a2 += p.y * fmaxf(fmaf(p.x, w.z, b.z), 0.f);
        a3 += p.y * fmaxf(fmaf(p.x, w.w, b.w), 0.f);
    }
    float dvi = self.y;
    ushort4 o;
    o.x = f2b(a0 * dvi);
    o.y = f2b(a1 * dvi);
    o.z = f2b(a2 * dvi);
    o.w = f2b(a3 * dvi);
    *(ushort4*)&M[(size_t)node * HDIM + c4] = o;
}

// pack W (f32 [256][256]) into bf16 MFMA fragment order; 2 matrices in 1 launch
__global__ __launch_bounds__(256) void k_packW2(const float* __restrict__ Wa,
                                                ushort* __restrict__ Wpa,
                                                const float* __restrict__ Wb,
                                                ushort* __restrict__ Wpb) {
    int bid = blockIdx.x;
    const float* W = (bid < 32) ? Wa : Wb;
    ushort* Wp = (bid < 32) ? Wpa : Wpb;
    int t = (bid & 31) * 256 + threadIdx.x;  // [0, 8192)
    int lane = t & 63;
    int nt = (t >> 6) & 15;
    int k0 = t >> 10;
    int col = nt * 16 + (lane & 15);
    int kb = k0 * 32 + (lane >> 4) * 8;
    ushort o[8];
#pragma unroll
    for (int j = 0; j < 8; ++j) o[j] = f2b(W[(size_t)(kb + j) * HDIM + col]);
    *(ushort4*)&Wp[(size_t)t * 8 + 0] = make_ushort4(o[0], o[1], o[2], o[3]);
    *(ushort4*)&Wp[(size_t)t * 8 + 4] = make_ushort4(o[4], o[5], o[6], o[7]);
}

// MFMA GEMM with bias+relu epilogue: C[node][f] = relu(sum_k A[node][k]W[k][f] + bias[f])
__global__ __launch_bounds__(256) void k_gemm_bias(const ushort* __restrict__ A,
                                                   const ushort* __restrict__ Wp,
                                                   const float* __restrict__ bias,
                                                   ushort* __restrict__ C) {
    int tid = threadIdx.x;
    int wave = tid >> 6, lane = tid & 63;
    int r0 = blockIdx.x * 128 + wave * 32;
    int kgrp = lane >> 4;
    int node0 = r0 + (lane & 15);
    int node1 = node0 + 16;
    bool ok0 = node0 < N_NODES, ok1 = node1 < N_NODES;

    f32x4 acc0[16], acc1[16];
#pragma unroll
    for (int nt = 0; nt < 16; ++nt) {
        acc0[nt] = (f32x4){0.f, 0.f, 0.f, 0.f};
        acc1[nt] = (f32x4){0.f, 0.f, 0.f, 0.f};
    }

    const ushort* ap0 = A + (size_t)(ok0 ? node0 : 0) * HDIM + kgrp * 8;
    const ushort* ap1 = A + (size_t)(ok1 ? node1 : 0) * HDIM + kgrp * 8;
#pragma unroll 1
    for (int k0 = 0; k0 < 8; ++k0) {
        bf16x8 b0 = *(const bf16x8*)(ap0 + k0 * 32);
        bf16x8 b1 = *(const bf16x8*)(ap1 + k0 * 32);
        if (!ok0) b0 = (bf16x8){0, 0, 0, 0, 0, 0, 0, 0};
        if (!ok1) b1 = (bf16x8){0, 0, 0, 0, 0, 0, 0, 0};
        const ushort* wp = Wp + ((size_t)k0 * 1024 + lane) * 8;
#pragma unroll
        for (int nt = 0; nt < 16; ++nt) {
            bf16x8 a = *(const bf16x8*)(wp + (size_t)nt * 512);
            acc0[nt] = __builtin_amdgcn_mfma_f32_16x16x32_bf16(a, b0, acc0[nt], 0, 0, 0);
            acc1[nt] = __builtin_amdgcn_mfma_f32_16x16x32_bf16(a, b1, acc1[nt], 0, 0, 0);
        }
    }

    if (ok0) {
        size_t base = (size_t)node0 * HDIM + kgrp * 4;
#pragma unroll
        for (int nt = 0; nt < 16; ++nt) {
            float4 bv = *(const float4*)&bias[nt * 16 + kgrp * 4];
            ushort4 o;
            o.x = f2b(fmaxf(acc0[nt][0] + bv.x, 0.f));
            o.y = f2b(fmaxf(acc0[nt][1] + bv.y, 0.f));
            o.z = f2b(fmaxf(acc0[nt][2] + bv.z, 0.f));
            o.w = f2b(fmaxf(acc0[nt][3] + bv.w, 0.f));
            *(ushort4*)&C[base + nt * 16] = o;
        }
    }
    if (ok1) {
        size_t base = (size_t)node1 * HDIM + kgrp * 4;
#pragma unroll
        for (int nt = 0; nt < 16; ++nt) {
            float4 bv = *(const float4*)&bias[nt * 16 + kgrp * 4];
            ushort4 o;
            o.x = f2b(fmaxf(acc1[nt][0] + bv.x, 0.f));
            o.y = f2b(fmaxf(acc1[nt][1] + bv.y, 0.f));
            o.z = f2b(fmaxf(acc1[nt][2] + bv.z, 0.f));
            o.w = f2b(fmaxf(acc1[nt][3] + bv.w, 0.f));
            *(ushort4*)&C[base + nt * 16] = o;
        }
    }
}

// MFMA GEMM with dinv epilogue (layer 3 pre-aggregation)
__global__ __launch_bounds__(256) void k_gemm_mfma(const ushort* __restrict__ A,
                                                   const ushort* __restrict__ Wp,
                                                   const float* __restrict__ dinv,
                                                   ushort* __restrict__ C) {
    int tid = threadIdx.x;
    int wave = tid >> 6, lane = tid & 63;
    int r0 = blockIdx.x * 128 + wave * 32;
    int kgrp = lane >> 4;
    int node0 = r0 + (lane & 15);
    int node1 = node0 + 16;
    bool ok0 = node0 < N_NODES, ok1 = node1 < N_NODES;

    f32x4 acc0[16], acc1[16];
#pragma unroll
    for (int nt = 0; nt < 16; ++nt) {
        acc0[nt] = (f32x4){0.f, 0.f, 0.f, 0.f};
        acc1[nt] = (f32x4){0.f, 0.f, 0.f, 0.f};
    }

    const ushort* ap0 = A + (size_t)(ok0 ? node0 : 0) * HDIM + kgrp * 8;
    const ushort* ap1 = A + (size_t)(ok1 ? node1 : 0) * HDIM + kgrp * 8;
#pragma unroll 1
    for (int k0 = 0; k0 < 8; ++k0) {
        bf16x8 b0 = *(const bf16x8*)(ap0 + k0 * 32);
        bf16x8 b1 = *(const bf16x8*)(ap1 + k0 * 32);
        if (!ok0) b0 = (bf16x8){0, 0, 0, 0, 0, 0, 0, 0};
        if (!ok1) b1 = (bf16x8){0, 0, 0, 0, 0, 0, 0, 0};
        const ushort* wp = Wp + ((size_t)k0 * 1024 + lane) * 8;
#pragma unroll
        for (int nt = 0; nt < 16; ++nt) {
            bf16x8 a = *(const bf16x8*)(wp + (size_t)nt * 512);
            acc0[nt] = __builtin_amdgcn_mfma_f32_16x16x32_bf16(a, b0, acc0[nt], 0, 0, 0);
            acc1[nt] = __builtin_amdgcn_mfma_f32_16x16x32_bf16(a, b1, acc1[nt], 0, 0, 0);
        }
    }

    if (ok0) {
        float dv = dinv[node0];
        size_t base = (size_t)node0 * HDIM + kgrp * 4;
#pragma unroll
        for (int nt = 0; nt < 16; ++nt) {
            ushort4 o;
            o.x = f2b(acc0[nt][0] * dv);
            o.y = f2b(acc0[nt][1] * dv);
            o.z = f2b(acc0[nt][2] * dv);
            o.w = f2b(acc0[nt][3] * dv);
            *(ushort4*)&C[base + nt * 16] = o;
        }
    }
    if (ok1) {
        float dv = dinv[node1];
        size_t base = (size_t)node1 * HDIM + kgrp * 4;
#pragma unroll
        for (int nt = 0; nt < 16; ++nt) {
            ushort4 o;
            o.x = f2b(acc1[nt][0] * dv);
            o.y = f2b(acc1[nt][1] * dv);
            o.z = f2b(acc1[nt][2] * dv);
            o.w = f2b(acc1[nt][3] * dv);
            *(ushort4*)&C[base + nt * 16] = o;
        }
    }
}

// aggregation (layer 3): h[i] = relu(dinv[i]*(g[i] + sum_src g[src]) + b)
__global__ __launch_bounds__(256) void k_agg(const ushort* __restrict__ g,
                                             const int* __restrict__ rowptr,
                                             const int* __restrict__ colv,
                                             const float* __restrict__ dinv,
                                             const float* __restrict__ bias,
                                             ushort* __restrict__ hout) {
    int wid = threadIdx.x >> 6, lane = threadIdx.x & 63;
    int node = blockIdx.x * 4 + wid;
    if (node >= N_NODES) return;
    int half = lane >> 5;
    int l32 = lane & 31;
    int c8 = l32 * 8;
    float acc[8];
    if (half == 0) {
        u16x8 v = *(const u16x8*)&g[(size_t)node * HDIM + c8];
#pragma unroll
        for (int j = 0; j < 8; ++j) acc[j] = b2f(v[j]);
    } else {
#pragma unroll
        for (int j = 0; j < 8; ++j) acc[j] = 0.f;
    }
    int s = rowptr[node], e = rowptr[node + 1];
    int i = s;
    for (; i + 8 <= e; i += 8) {
        int base = i + half * 4;
        int n0 = colv[base + 0];
        int n1 = colv[base + 1];
        int n2 = colv[base + 2];
        int n3 = colv[base + 3];
        u16x8 v0 = *(const u16x8*)&g[(size_t)n0 * HDIM + c8];
        u16x8 v1 = *(const u16x8*)&g[(size_t)n1 * HDIM + c8];
        u16x8 v2 = *(const u16x8*)&g[(size_t)n2 * HDIM + c8];
        u16x8 v3 = *(const u16x8*)&g[(size_t)n3 * HDIM + c8];
#pragma unroll
        for (int j = 0; j < 8; ++j)
            acc[j] += (b2f(v0[j]) + b2f(v1[j])) + (b2f(v2[j]) + b2f(v3[j]));
    }
    if (i + 4 <= e) {
        int base = i + half * 2;
        int n0 = colv[base + 0];
        int n1 = colv[base + 1];
        u16x8 v0 = *(const u16x8*)&g[(size_t)n0 * HDIM + c8];
        u16x8 v1 = *(const u16x8*)&g[(size_t)n1 * HDIM + c8];
#pragma unroll
        for (int j = 0; j < 8; ++j) acc[j] += b2f(v0[j]) + b2f(v1[j]);
        i += 4;
    }
    if (i + 2 <= e) {
        int n = colv[i + half];
        u16x8 v = *(const u16x8*)&g[(size_t)n * HDIM + c8];
#pragma unroll
        for (int j = 0; j < 8; ++j) acc[j] += b2f(v[j]);
        i += 2;
    }
    if (i < e && half == 0) {
        int n = colv[i];
        u16x8 v = *(const u16x8*)&g[(size_t)n * HDIM + c8];
#pragma unroll
        for (int j = 0; j < 8; ++j) acc[j] += b2f(v[j]);
    }
#pragma unroll
    for (int j = 0; j < 8; ++j) acc[j] += __shfl_xor(acc[j], 32);
    if (half == 0) {
        float dv = dinv[node];
        float4 bl = *(const float4*)&bias[c8];
        float4 bh = *(const float4*)&bias[c8 + 4];
        float bj[8] = {bl.x, bl.y, bl.z, bl.w, bh.x, bh.y, bh.z, bh.w};
        u16x8 ov;
#pragma unroll
        for (int j = 0; j < 8; ++j)
            ov[j] = f2b(fmaxf(fmaf(acc[j], dv, bj[j]), 0.f));
        *(u16x8*)&hout[(size_t)node * HDIM + c8] = ov;
    }
}

__global__ __launch_bounds__(128) void k_bounds(const int* __restrict__ batch,
                                                int* __restrict__ startb,
                                                float* __restrict__ pooled) {
    int t = threadIdx.x;
    if (t <= NGRAPH) {
        int lo = 0, hi = N_NODES;
        while (lo < hi) {
            int mid = (lo + hi) >> 1;
            if (batch[mid] < t) lo = mid + 1; else hi = mid;
        }
        startb[t] = lo;
    }
    for (int i = t; i < NGRAPH * HDIM; i += 128) pooled[i] = 0.f;
}

__global__ __launch_bounds__(256) void k_pool(const ushort* __restrict__ h,
                                              const int* __restrict__ startb,
                                              float* __restrict__ pooled) {
    int b = blockIdx.x >> 3, c = blockIdx.x & 7;
    int s0 = startb[b], e0 = startb[b + 1];
    int len = e0 - s0;
    if (len <= 0) return;
    int per = (len + 7) >> 3;
    int is = s0 + c * per;
    int ie = min(is + per, e0);
    if (is >= ie) return;
    int j = threadIdx.x;
    float sum = 0.f;
    for (int n = is; n < ie; ++n) sum += b2f(h[(size_t)n * HDIM + j]);
    atomicAdd(&pooled[b * HDIM + j], sum);
}

__global__ __launch_bounds__(128) void k_mlp(const float* __restrict__ pooled,
                                             const int* __restrict__ startb,
                                             const float* __restrict__ svm,
                                             const float* __restrict__ Wf1,
                                             const float* __restrict__ bf1,
                                             const float* __restrict__ Wf2,
                                             const float* __restrict__ bf2,
                                             float* __restrict__ out) {
    __shared__ float fl[257];
    __shared__ float hl[128];
    int b = blockIdx.x;
    int j = threadIdx.x;
    float cntb = fmaxf((float)(startb[b + 1] - startb[b]), 1.0f);
    for (int k = j; k < 256; k += 128) fl[k] = pooled[b * HDIM + k] / cntb;
    if (j == 0) fl[256] = svm[b];
    __syncthreads();
    float acc = bf1[j];
    for (int k = 0; k < 257; ++k) acc = fmaf(fl[k], Wf1[k * 128 + j], acc);
    hl[j] = fmaxf(acc, 0.f);
    __syncthreads();
    if (j < 6) {
        float o = bf2[j];
        for (int k = 0; k < 128; ++k) o = fmaf(hl[k], Wf2[k * 6 + j], o);
        out[b * 6 + j] = o;
    }
}

static inline size_t al256(size_t x) { return (x + 255) & ~(size_t)255; }

extern "C" void kernel_launch(void* const* d_in, const int* in_sizes, int n_in,
                              void* d_out, int out_size, void* d_ws, size_t ws_size,
                              hipStream_t stream) {
    const float* x    = (const float*)d_in[0];
    const int*   ei   = (const int*)d_in[1];
    const int*   batch= (const int*)d_in[2];
    const float* svm  = (const float*)d_in[3];
    const float* W1   = (const float*)d_in[4];
    const float* b1   = (const float*)d_in[5];
    const float* W2   = (const float*)d_in[6];
    const float* b2   = (const float*)d_in[7];
    const float* W3   = (const float*)d_in[8];
    const float* b3   = (const float*)d_in[9];
    const float* Wf1  = (const float*)d_in[10];
    const float* bf1  = (const float*)d_in[11];
    const float* Wf2  = (const float*)d_in[12];
    const float* bf2  = (const float*)d_in[13];
    float* out = (float*)d_out;

    char* w = (char*)d_ws;
    int*    cnt    = (int*)w;    w += al256((size_t)N_NODES * 4);
    int*    rowptr = (int*)w;    w += al256((size_t)(N_NODES + 1) * 4);
    int*    slot   = (int*)w;    w += al256((size_t)N_EDGES * 4);
    int*    colv   = (int*)w;    w += al256((size_t)N_EDGES * 4);
    float*  dinv   = (float*)w;  w += al256((size_t)N_NODES * 4);
    float*  xd     = (float*)w;  w += al256((size_t)N_NODES * 4);
    float2* sd     = (float2*)w; w += al256((size_t)N_NODES * 8);
    int*    startb = (int*)w;    w += al256(65 * 4);
    int*    bsum   = (int*)w;    w += al256((size_t)SCAN_NB * 4);
    float*  pooled = (float*)w;  w += al256((size_t)NGRAPH * HDIM * 4);
    ushort* Wp2    = (ushort*)w; w += al256((size_t)8 * 16 * 64 * 8 * 2);
    ushort* Wp3    = (ushort*)w; w += al256((size_t)8 * 16 * 64 * 8 * 2);
    ushort* bigA   = (ushort*)w; w += al256((size_t)N_NODES * HDIM * 2);
    ushort* bigB   = (ushort*)w; w += al256((size_t)N_NODES * HDIM * 2);

    const int nblkN = (N_NODES + 255) / 256;
    const int nblkE = (N_EDGES + 255) / 256;
    const int nblkW = (N_NODES + 3) / 4;
    const int nblkG = (N_NODES + 127) / 128;

    // CSR build
    hipMemsetAsync(cnt, 0, (size_t)N_NODES * 4, stream);
    k_count<<<nblkE, 256, 0, stream>>>(ei, cnt, slot);
    k_scan1<<<SCAN_NB, SCAN_BLK, 0, stream>>>(cnt, rowptr, bsum);
    k_scan2<<<1, 128, 0, stream>>>(bsum);
    k_dinv_fix<<<nblkN, 256, 0, stream>>>(cnt, x, bsum, dinv, xd, rowptr);
    k_fill<<<nblkE, 256, 0, stream>>>(ei, rowptr, slot, colv);

    // W packing (both layers, one launch)
    k_packW2<<<64, 256, 0, stream>>>(W2, Wp2, W3, Wp3);

    // layer 1 scalar agg -> (s, dinv) pairs
    k_s<<<nblkN, 256, 0, stream>>>(rowptr, colv, xd, dinv, sd);

    // layer 2: rank-1 aggregation (scalar gather only) -> M, then GEMM+bias+relu
    k_aggM<<<nblkW, 256, 0, stream>>>(rowptr, colv, sd, W1, b1, bigB);
    k_gemm_bias<<<nblkG, 256, 0, stream>>>(bigB, Wp2, b2, bigA);

    // layer 3: GEMM (dinv epilogue) then row-gather aggregation
    k_gemm_mfma<<<nblkG, 256, 0, stream>>>(bigA, Wp3, dinv, bigB);
    k_agg<<<nblkW, 256, 0, stream>>>(bigB, rowptr, colv, dinv, b3, bigA);

    // pooling + head
    k_bounds<<<1, 128, 0, stream>>>(batch, startb, pooled);
    k_pool<<<NGRAPH * 8, 256, 0, stream>>>(bigA, startb, pooled);
    k_mlp<<<NGRAPH, 128, 0, stream>>>(pooled, startb, svm, Wf1, bf1, Wf2, bf2, out);
}

// Round 8
// 512.071 us; speedup vs baseline: 1.5255x; 1.0519x over previous
//
#include <hip/hip_runtime.h>
#include <math.h>

#define N_NODES 100000
#define N_EDGES 1600000
#define HDIM    256
#define NGRAPH  64

#define SCAN_BLK 1024
#define SCAN_NB  ((N_NODES + SCAN_BLK - 1) / SCAN_BLK)  // 98

typedef __attribute__((ext_vector_type(8))) short bf16x8;
typedef __attribute__((ext_vector_type(4))) float f32x4;
typedef __attribute__((ext_vector_type(8))) unsigned short u16x8;

__device__ __forceinline__ ushort f2b(float f) {
    union { float f; unsigned u; } x; x.f = f;
    unsigned u = x.u;
    unsigned r = u + 0x7fffu + ((u >> 16) & 1u);
    return (ushort)(r >> 16);
}
__device__ __forceinline__ float b2f(ushort h) {
    union { unsigned u; float f; } x; x.u = ((unsigned)h) << 16;
    return x.f;
}

// ---------------- CSR build ----------------
__global__ void k_count(const int* __restrict__ ei, int* __restrict__ cnt,
                        int* __restrict__ slot) {
    int e = blockIdx.x * blockDim.x + threadIdx.x;
    if (e < N_EDGES) slot[e] = atomicAdd(&cnt[ei[N_EDGES + e]], 1);
}

__global__ __launch_bounds__(1024) void k_scan1(const int* __restrict__ cnt,
                                                int* __restrict__ rowptr,
                                                int* __restrict__ bsum) {
    __shared__ int lds[SCAN_BLK];
    int t = threadIdx.x;
    int i = blockIdx.x * SCAN_BLK + t;
    int v = (i < N_NODES) ? cnt[i] : 0;
    lds[t] = v;
    __syncthreads();
    for (int off = 1; off < SCAN_BLK; off <<= 1) {
        int u = (t >= off) ? lds[t - off] : 0;
        __syncthreads();
        lds[t] += u;
        __syncthreads();
    }
    if (i < N_NODES) rowptr[i] = lds[t] - v;
    if (t == SCAN_BLK - 1) bsum[blockIdx.x] = lds[t];
}

__global__ __launch_bounds__(128) void k_scan2(int* __restrict__ bsum) {
    __shared__ int lds[128];
    int t = threadIdx.x;
    int v = (t < SCAN_NB) ? bsum[t] : 0;
    lds[t] = v;
    __syncthreads();
    for (int off = 1; off < 128; off <<= 1) {
        int u = (t >= off) ? lds[t - off] : 0;
        __syncthreads();
        lds[t] += u;
        __syncthreads();
    }
    if (t < SCAN_NB) bsum[t] = lds[t] - v;
}

__global__ void k_dinv_fix(const int* __restrict__ cnt, const float* __restrict__ x,
                           const int* __restrict__ bsum,
                           float* __restrict__ dinv, float* __restrict__ xd,
                           int* __restrict__ rowptr) {
    int i = blockIdx.x * blockDim.x + threadIdx.x;
    if (i < N_NODES) {
        rowptr[i] += bsum[i >> 10];
        float d = (float)(cnt[i] + 1);
        float dv = 1.0f / sqrtf(d);
        dinv[i] = dv;
        xd[i] = x[i] * dv;
        if (i == 0) rowptr[N_NODES] = N_EDGES;
    }
}

__global__ void k_fill(const int* __restrict__ ei, const int* __restrict__ rowptr,
                       const int* __restrict__ slot, int* __restrict__ colv) {
    int e = blockIdx.x * blockDim.x + threadIdx.x;
    if (e < N_EDGES) {
        int d = ei[N_EDGES + e];
        colv[rowptr[d] + slot[e]] = ei[e];
    }
}

// layer-1 scalar aggregation, wave per node, lane-parallel gather
__global__ __launch_bounds__(256) void k_s(const int* __restrict__ rowptr,
                                           const int* __restrict__ colv,
                                           const float* __restrict__ xd,
                                           const float* __restrict__ dinv,
                                           float2* __restrict__ sd) {
    int wid = threadIdx.x >> 6, lane = threadIdx.x & 63;
    int node = blockIdx.x * 4 + wid;
    if (node >= N_NODES) return;
    int s = rowptr[node], e = rowptr[node + 1];
    float acc = 0.f;
    for (int idx = s + lane; idx < e; idx += 64) acc += xd[colv[idx]];
#pragma unroll
    for (int off = 32; off; off >>= 1) acc += __shfl_xor(acc, off);
    if (lane == 0) {
        float dv = dinv[node];
        sd[node] = make_float2(dv * (acc + xd[node]), dv);
    }
}

// Layer-2 aggregation via rank-1 structure (exact fp32), lane-parallel:
// lane gathers one neighbor's (s,dinv); shfl-broadcast; each lane owns 4 feats.
__global__ __launch_bounds__(256) void k_aggM(const int* __restrict__ rowptr,
                                              const int* __restrict__ colv,
                                              const float2* __restrict__ sd,
                                              const float* __restrict__ W1,
                                              const float* __restrict__ b1,
                                              ushort* __restrict__ M) {
    int wid = threadIdx.x >> 6, lane = threadIdx.x & 63;
    int node = blockIdx.x * 4 + wid;
    if (node >= N_NODES) return;
    int c4 = lane * 4;
    float4 w = *(const float4*)&W1[c4];
    float4 b = *(const float4*)&b1[c4];
    float2 self = sd[node];
    float a0 = self.y * fmaxf(fmaf(self.x, w.x, b.x), 0.f);
    float a1 = self.y * fmaxf(fmaf(self.x, w.y, b.y), 0.f);
    float a2 = self.y * fmaxf(fmaf(self.x, w.z, b.z), 0.f);
    float a3 = self.y * fmaxf(fmaf(self.x, w.w, b.w), 0.f);
    int s = rowptr[node], e = rowptr[node + 1];
    for (int base = s; base < e; base += 64) {
        int idx = base + lane;
        float2 p = make_float2(0.f, 0.f);
        if (idx < e) p = sd[colv[idx]];
        int rem = min(64, e - base);
        for (int k = 0; k < rem; ++k) {
            float ps = __shfl(p.x, k);
            float pd = __shfl(p.y, k);
            a0 += pd * fmaxf(fmaf(ps, w.x, b.x), 0.f);
            a1 += pd * fmaxf(fmaf(ps, w.y, b.y), 0.f);
            a2 += pd * fmaxf(fmaf(ps, w.z, b.z), 0.f);
            a3 += pd * fmaxf(fmaf(ps, w.w, b.w), 0.f);
        }
    }
    float dvi = self.y;
    ushort4 o;
    o.x = f2b(a0 * dvi);
    o.y = f2b(a1 * dvi);
    o.z = f2b(a2 * dvi);
    o.w = f2b(a3 * dvi);
    *(ushort4*)&M[(size_t)node * HDIM + c4] = o;
}

// pack W (f32 [256][256]) into bf16 MFMA fragment order; 2 matrices in 1 launch
__global__ __launch_bounds__(256) void k_packW2(const float* __restrict__ Wa,
                                                ushort* __restrict__ Wpa,
                                                const float* __restrict__ Wb,
                                                ushort* __restrict__ Wpb) {
    int bid = blockIdx.x;
    const float* W = (bid < 32) ? Wa : Wb;
    ushort* Wp = (bid < 32) ? Wpa : Wpb;
    int t = (bid & 31) * 256 + threadIdx.x;  // [0, 8192)
    int lane = t & 63;
    int nt = (t >> 6) & 15;
    int k0 = t >> 10;
    int col = nt * 16 + (lane & 15);
    int kb = k0 * 32 + (lane >> 4) * 8;
    ushort o[8];
#pragma unroll
    for (int j = 0; j < 8; ++j) o[j] = f2b(W[(size_t)(kb + j) * HDIM + col]);
    *(ushort4*)&Wp[(size_t)t * 8 + 0] = make_ushort4(o[0], o[1], o[2], o[3]);
    *(ushort4*)&Wp[(size_t)t * 8 + 4] = make_ushort4(o[4], o[5], o[6], o[7]);
}

// MFMA GEMM with bias+relu epilogue
__global__ __launch_bounds__(256) void k_gemm_bias(const ushort* __restrict__ A,
                                                   const ushort* __restrict__ Wp,
                                                   const float* __restrict__ bias,
                                                   ushort* __restrict__ C) {
    int tid = threadIdx.x;
    int wave = tid >> 6, lane = tid & 63;
    int r0 = blockIdx.x * 128 + wave * 32;
    int kgrp = lane >> 4;
    int node0 = r0 + (lane & 15);
    int node1 = node0 + 16;
    bool ok0 = node0 < N_NODES, ok1 = node1 < N_NODES;

    f32x4 acc0[16], acc1[16];
#pragma unroll
    for (int nt = 0; nt < 16; ++nt) {
        acc0[nt] = (f32x4){0.f, 0.f, 0.f, 0.f};
        acc1[nt] = (f32x4){0.f, 0.f, 0.f, 0.f};
    }

    const ushort* ap0 = A + (size_t)(ok0 ? node0 : 0) * HDIM + kgrp * 8;
    const ushort* ap1 = A + (size_t)(ok1 ? node1 : 0) * HDIM + kgrp * 8;
#pragma unroll 1
    for (int k0 = 0; k0 < 8; ++k0) {
        bf16x8 b0 = *(const bf16x8*)(ap0 + k0 * 32);
        bf16x8 b1 = *(const bf16x8*)(ap1 + k0 * 32);
        if (!ok0) b0 = (bf16x8){0, 0, 0, 0, 0, 0, 0, 0};
        if (!ok1) b1 = (bf16x8){0, 0, 0, 0, 0, 0, 0, 0};
        const ushort* wp = Wp + ((size_t)k0 * 1024 + lane) * 8;
#pragma unroll
        for (int nt = 0; nt < 16; ++nt) {
            bf16x8 a = *(const bf16x8*)(wp + (size_t)nt * 512);
            acc0[nt] = __builtin_amdgcn_mfma_f32_16x16x32_bf16(a, b0, acc0[nt], 0, 0, 0);
            acc1[nt] = __builtin_amdgcn_mfma_f32_16x16x32_bf16(a, b1, acc1[nt], 0, 0, 0);
        }
    }

    if (ok0) {
        size_t base = (size_t)node0 * HDIM + kgrp * 4;
#pragma unroll
        for (int nt = 0; nt < 16; ++nt) {
            float4 bv = *(const float4*)&bias[nt * 16 + kgrp * 4];
            ushort4 o;
            o.x = f2b(fmaxf(acc0[nt][0] + bv.x, 0.f));
            o.y = f2b(fmaxf(acc0[nt][1] + bv.y, 0.f));
            o.z = f2b(fmaxf(acc0[nt][2] + bv.z, 0.f));
            o.w = f2b(fmaxf(acc0[nt][3] + bv.w, 0.f));
            *(ushort4*)&C[base + nt * 16] = o;
        }
    }
    if (ok1) {
        size_t base = (size_t)node1 * HDIM + kgrp * 4;
#pragma unroll
        for (int nt = 0; nt < 16; ++nt) {
            float4 bv = *(const float4*)&bias[nt * 16 + kgrp * 4];
            ushort4 o;
            o.x = f2b(fmaxf(acc1[nt][0] + bv.x, 0.f));
            o.y = f2b(fmaxf(acc1[nt][1] + bv.y, 0.f));
            o.z = f2b(fmaxf(acc1[nt][2] + bv.z, 0.f));
            o.w = f2b(fmaxf(acc1[nt][3] + bv.w, 0.f));
            *(ushort4*)&C[base + nt * 16] = o;
        }
    }
}

// MFMA GEMM with dinv epilogue (layer 3 pre-aggregation)
__global__ __launch_bounds__(256) void k_gemm_mfma(const ushort* __restrict__ A,
                                                   const ushort* __restrict__ Wp,
                                                   const float* __restrict__ dinv,
                                                   ushort* __restrict__ C) {
    int tid = threadIdx.x;
    int wave = tid >> 6, lane = tid & 63;
    int r0 = blockIdx.x * 128 + wave * 32;
    int kgrp = lane >> 4;
    int node0 = r0 + (lane & 15);
    int node1 = node0 + 16;
    bool ok0 = node0 < N_NODES, ok1 = node1 < N_NODES;

    f32x4 acc0[16], acc1[16];
#pragma unroll
    for (int nt = 0; nt < 16; ++nt) {
        acc0[nt] = (f32x4){0.f, 0.f, 0.f, 0.f};
        acc1[nt] = (f32x4){0.f, 0.f, 0.f, 0.f};
    }

    const ushort* ap0 = A + (size_t)(ok0 ? node0 : 0) * HDIM + kgrp * 8;
    const ushort* ap1 = A + (size_t)(ok1 ? node1 : 0) * HDIM + kgrp * 8;
#pragma unroll 1
    for (int k0 = 0; k0 < 8; ++k0) {
        bf16x8 b0 = *(const bf16x8*)(ap0 + k0 * 32);
        bf16x8 b1 = *(const bf16x8*)(ap1 + k0 * 32);
        if (!ok0) b0 = (bf16x8){0, 0, 0, 0, 0, 0, 0, 0};
        if (!ok1) b1 = (bf16x8){0, 0, 0, 0, 0, 0, 0, 0};
        const ushort* wp = Wp + ((size_t)k0 * 1024 + lane) * 8;
#pragma unroll
        for (int nt = 0; nt < 16; ++nt) {
            bf16x8 a = *(const bf16x8*)(wp + (size_t)nt * 512);
            acc0[nt] = __builtin_amdgcn_mfma_f32_16x16x32_bf16(a, b0, acc0[nt], 0, 0, 0);
            acc1[nt] = __builtin_amdgcn_mfma_f32_16x16x32_bf16(a, b1, acc1[nt], 0, 0, 0);
        }
    }

    if (ok0) {
        float dv = dinv[node0];
        size_t base = (size_t)node0 * HDIM + kgrp * 4;
#pragma unroll
        for (int nt = 0; nt < 16; ++nt) {
            ushort4 o;
            o.x = f2b(acc0[nt][0] * dv);
            o.y = f2b(acc0[nt][1] * dv);
            o.z = f2b(acc0[nt][2] * dv);
            o.w = f2b(acc0[nt][3] * dv);
            *(ushort4*)&C[base + nt * 16] = o;
        }
    }
    if (ok1) {
        float dv = dinv[node1];
        size_t base = (size_t)node1 * HDIM + kgrp * 4;
#pragma unroll
        for (int nt = 0; nt < 16; ++nt) {
            ushort4 o;
            o.x = f2b(acc1[nt][0] * dv);
            o.y = f2b(acc1[nt][1] * dv);
            o.z = f2b(acc1[nt][2] * dv);
            o.w = f2b(acc1[nt][3] * dv);
            *(ushort4*)&C[base + nt * 16] = o;
        }
    }
}

// aggregation (layer 3): h[i] = relu(dinv[i]*(g[i] + sum_src g[src]) + b)
__global__ __launch_bounds__(256) void k_agg(const ushort* __restrict__ g,
                                             const int* __restrict__ rowptr,
                                             const int* __restrict__ colv,
                                             const float* __restrict__ dinv,
                                             const float* __restrict__ bias,
                                             ushort* __restrict__ hout) {
    int wid = threadIdx.x >> 6, lane = threadIdx.x & 63;
    int node = blockIdx.x * 4 + wid;
    if (node >= N_NODES) return;
    int half = lane >> 5;
    int l32 = lane & 31;
    int c8 = l32 * 8;
    float acc[8];
    if (half == 0) {
        u16x8 v = *(const u16x8*)&g[(size_t)node * HDIM + c8];
#pragma unroll
        for (int j = 0; j < 8; ++j) acc[j] = b2f(v[j]);
    } else {
#pragma unroll
        for (int j = 0; j < 8; ++j) acc[j] = 0.f;
    }
    int s = rowptr[node], e = rowptr[node + 1];
    int i = s;
    for (; i + 8 <= e; i += 8) {
        int base = i + half * 4;
        int n0 = colv[base + 0];
        int n1 = colv[base + 1];
        int n2 = colv[base + 2];
        int n3 = colv[base + 3];
        u16x8 v0 = *(const u16x8*)&g[(size_t)n0 * HDIM + c8];
        u16x8 v1 = *(const u16x8*)&g[(size_t)n1 * HDIM + c8];
        u16x8 v2 = *(const u16x8*)&g[(size_t)n2 * HDIM + c8];
        u16x8 v3 = *(const u16x8*)&g[(size_t)n3 * HDIM + c8];
#pragma unroll
        for (int j = 0; j < 8; ++j)
            acc[j] += (b2f(v0[j]) + b2f(v1[j])) + (b2f(v2[j]) + b2f(v3[j]));
    }
    if (i + 4 <= e) {
        int base = i + half * 2;
        int n0 = colv[base + 0];
        int n1 = colv[base + 1];
        u16x8 v0 = *(const u16x8*)&g[(size_t)n0 * HDIM + c8];
        u16x8 v1 = *(const u16x8*)&g[(size_t)n1 * HDIM + c8];
#pragma unroll
        for (int j = 0; j < 8; ++j) acc[j] += b2f(v0[j]) + b2f(v1[j]);
        i += 4;
    }
    if (i + 2 <= e) {
        int n = colv[i + half];
        u16x8 v = *(const u16x8*)&g[(size_t)n * HDIM + c8];
#pragma unroll
        for (int j = 0; j < 8; ++j) acc[j] += b2f(v[j]);
        i += 2;
    }
    if (i < e && half == 0) {
        int n = colv[i];
        u16x8 v = *(const u16x8*)&g[(size_t)n * HDIM + c8];
#pragma unroll
        for (int j = 0; j < 8; ++j) acc[j] += b2f(v[j]);
    }
#pragma unroll
    for (int j = 0; j < 8; ++j) acc[j] += __shfl_xor(acc[j], 32);
    if (half == 0) {
        float dv = dinv[node];
        float4 bl = *(const float4*)&bias[c8];
        float4 bh = *(const float4*)&bias[c8 + 4];
        float bj[8] = {bl.x, bl.y, bl.z, bl.w, bh.x, bh.y, bh.z, bh.w};
        u16x8 ov;
#pragma unroll
        for (int j = 0; j < 8; ++j)
            ov[j] = f2b(fmaxf(fmaf(acc[j], dv, bj[j]), 0.f));
        *(u16x8*)&hout[(size_t)node * HDIM + c8] = ov;
    }
}

__global__ __launch_bounds__(128) void k_bounds(const int* __restrict__ batch,
                                                int* __restrict__ startb,
                                                float* __restrict__ pooled) {
    int t = threadIdx.x;
    if (t <= NGRAPH) {
        int lo = 0, hi = N_NODES;
        while (lo < hi) {
            int mid = (lo + hi) >> 1;
            if (batch[mid] < t) lo = mid + 1; else hi = mid;
        }
        startb[t] = lo;
    }
    for (int i = t; i < NGRAPH * HDIM; i += 128) pooled[i] = 0.f;
}

__global__ __launch_bounds__(256) void k_pool(const ushort* __restrict__ h,
                                              const int* __restrict__ startb,
                                              float* __restrict__ pooled) {
    int b = blockIdx.x >> 3, c = blockIdx.x & 7;
    int s0 = startb[b], e0 = startb[b + 1];
    int len = e0 - s0;
    if (len <= 0) return;
    int per = (len + 7) >> 3;
    int is = s0 + c * per;
    int ie = min(is + per, e0);
    if (is >= ie) return;
    int j = threadIdx.x;
    float sum = 0.f;
    for (int n = is; n < ie; ++n) sum += b2f(h[(size_t)n * HDIM + j]);
    atomicAdd(&pooled[b * HDIM + j], sum);
}

__global__ __launch_bounds__(128) void k_mlp(const float* __restrict__ pooled,
                                             const int* __restrict__ startb,
                                             const float* __restrict__ svm,
                                             const float* __restrict__ Wf1,
                                             const float* __restrict__ bf1,
                                             const float* __restrict__ Wf2,
                                             const float* __restrict__ bf2,
                                             float* __restrict__ out) {
    __shared__ float fl[257];
    __shared__ float hl[128];
    int b = blockIdx.x;
    int j = threadIdx.x;
    float cntb = fmaxf((float)(startb[b + 1] - startb[b]), 1.0f);
    for (int k = j; k < 256; k += 128) fl[k] = pooled[b * HDIM + k] / cntb;
    if (j == 0) fl[256] = svm[b];
    __syncthreads();
    float acc = bf1[j];
    for (int k = 0; k < 257; ++k) acc = fmaf(fl[k], Wf1[k * 128 + j], acc);
    hl[j] = fmaxf(acc, 0.f);
    __syncthreads();
    if (j < 6) {
        float o = bf2[j];
        for (int k = 0; k < 128; ++k) o = fmaf(hl[k], Wf2[k * 6 + j], o);
        out[b * 6 + j] = o;
    }
}

static inline size_t al256(size_t x) { return (x + 255) & ~(size_t)255; }

extern "C" void kernel_launch(void* const* d_in, const int* in_sizes, int n_in,
                              void* d_out, int out_size, void* d_ws, size_t ws_size,
                              hipStream_t stream) {
    const float* x    = (const float*)d_in[0];
    const int*   ei   = (const int*)d_in[1];
    const int*   batch= (const int*)d_in[2];
    const float* svm  = (const float*)d_in[3];
    const float* W1   = (const float*)d_in[4];
    const float* b1   = (const float*)d_in[5];
    const float* W2   = (const float*)d_in[6];
    const float* b2   = (const float*)d_in[7];
    const float* W3   = (const float*)d_in[8];
    const float* b3   = (const float*)d_in[9];
    const float* Wf1  = (const float*)d_in[10];
    const float* bf1  = (const float*)d_in[11];
    const float* Wf2  = (const float*)d_in[12];
    const float* bf2  = (const float*)d_in[13];
    float* out = (float*)d_out;

    char* w = (char*)d_ws;
    int*    cnt    = (int*)w;    w += al256((size_t)N_NODES * 4);
    int*    rowptr = (int*)w;    w += al256((size_t)(N_NODES + 1) * 4);
    int*    slot   = (int*)w;    w += al256((size_t)N_EDGES * 4);
    int*    colv   = (int*)w;    w += al256((size_t)N_EDGES * 4);
    float*  dinv   = (float*)w;  w += al256((size_t)N_NODES * 4);
    float*  xd     = (float*)w;  w += al256((size_t)N_NODES * 4);
    float2* sd     = (float2*)w; w += al256((size_t)N_NODES * 8);
    int*    startb = (int*)w;    w += al256(65 * 4);
    int*    bsum   = (int*)w;    w += al256((size_t)SCAN_NB * 4);
    float*  pooled = (float*)w;  w += al256((size_t)NGRAPH * HDIM * 4);
    ushort* Wp2    = (ushort*)w; w += al256((size_t)8 * 16 * 64 * 8 * 2);
    ushort* Wp3    = (ushort*)w; w += al256((size_t)8 * 16 * 64 * 8 * 2);
    ushort* bigA   = (ushort*)w; w += al256((size_t)N_NODES * HDIM * 2);
    ushort* bigB   = (ushort*)w; w += al256((size_t)N_NODES * HDIM * 2);

    const int nblkN = (N_NODES + 255) / 256;
    const int nblkE = (N_EDGES + 255) / 256;
    const int nblkW = (N_NODES + 3) / 4;
    const int nblkG = (N_NODES + 127) / 128;

    // CSR build
    hipMemsetAsync(cnt, 0, (size_t)N_NODES * 4, stream);
    k_count<<<nblkE, 256, 0, stream>>>(ei, cnt, slot);
    k_scan1<<<SCAN_NB, SCAN_BLK, 0, stream>>>(cnt, rowptr, bsum);
    k_scan2<<<1, 128, 0, stream>>>(bsum);
    k_dinv_fix<<<nblkN, 256, 0, stream>>>(cnt, x, bsum, dinv, xd, rowptr);
    k_fill<<<nblkE, 256, 0, stream>>>(ei, rowptr, slot, colv);

    // W packing (both layers, one launch)
    k_packW2<<<64, 256, 0, stream>>>(W2, Wp2, W3, Wp3);

    // layer 1 scalar agg -> (s, dinv) pairs (wave per node)
    k_s<<<nblkW, 256, 0, stream>>>(rowptr, colv, xd, dinv, sd);

    // layer 2: rank-1 aggregation (lane-parallel scalar gather) -> M, then GEMM
    k_aggM<<<nblkW, 256, 0, stream>>>(rowptr, colv, sd, W1, b1, bigB);
    k_gemm_bias<<<nblkG, 256, 0, stream>>>(bigB, Wp2, b2, bigA);

    // layer 3: GEMM (dinv epilogue) then row-gather aggregation
    k_gemm_mfma<<<nblkG, 256, 0, stream>>>(bigA, Wp3, dinv, bigB);
    k_agg<<<nblkW, 256, 0, stream>>>(bigB, rowptr, colv, dinv, b3, bigA);

    // pooling + head
    k_bounds<<<1, 128, 0, stream>>>(batch, startb, pooled);
    k_pool<<<NGRAPH * 8, 256, 0, stream>>>(bigA, startb, pooled);
    k_mlp<<<NGRAPH, 128, 0, stream>>>(pooled, startb, svm, Wf1, bf1, Wf2, bf2, out);
}